// Round 11
// baseline (1159.868 us; speedup 1.0000x reference)
//
#include <hip/hip_runtime.h>

#define NN 100000
#define EE 320000

typedef unsigned int uint32;
typedef __attribute__((ext_vector_type(8))) short bf16x8;
typedef __attribute__((ext_vector_type(4))) float f32x4;
typedef __attribute__((ext_vector_type(16))) float f32x16;

__device__ __forceinline__ float4 ld4(const float* p){ return *(const float4*)p; }
__device__ __forceinline__ void st4(float* p, const float4 v){ *(float4*)p = v; }
__device__ __forceinline__ float sigm(float x){ return 1.f/(1.f + expf(-x)); }
__device__ __forceinline__ short f2b(float f){
  union { float f; uint32 u; } v; v.f = f;
  uint32 r = (v.u + 0x7FFFu + ((v.u>>16)&1u)) >> 16;   // RNE
  return (short)r;
}
__device__ __forceinline__ float b2f(short s){
  union { uint32 u; float f; } v; v.u = ((uint32)(unsigned short)s) << 16; return v.f;
}

constexpr int EM_STORE=0, EM_BRELU=1, EM_BNLK=2;

// ---------------------------------------------------------------------------
// Generic fp32 tiled GEMM (node path): 64 rows/block, BK=16, 256 threads.
// ---------------------------------------------------------------------------
template<int K,int NOUT,int EM>
__global__ __launch_bounds__(256) void gemm_k(
    const float* __restrict__ A,
    const float* __restrict__ W, const float* __restrict__ bias,
    const float* __restrict__ bng,
    float* __restrict__ C, int M)
{
  constexpr int CN = NOUT/16;
  __shared__ float As[16][68];
  __shared__ float Ws[16][NOUT];
  const int t  = threadIdx.x;
  const int tx = t & 15, ty = t >> 4;
  const int row0 = blockIdx.x * 64;

  float acc[4][CN];
  #pragma unroll
  for (int i=0;i<4;i++)
    #pragma unroll
    for (int j=0;j<CN;j++) acc[i][j]=0.f;

  const int r_st  = t >> 2;
  const int kq_st = (t & 3) * 4;

  for (int k0=0;k0<K;k0+=16) {
    {
      float4 v = make_float4(0.f,0.f,0.f,0.f);
      const int gr = row0 + r_st;
      if (gr < M) v = ld4(A + (size_t)gr*K + k0 + kq_st);
      As[kq_st+0][r_st]=v.x; As[kq_st+1][r_st]=v.y;
      As[kq_st+2][r_st]=v.z; As[kq_st+3][r_st]=v.w;
    }
    {
      constexpr int C4 = NOUT/4;
      for (int i=t;i<16*C4;i+=256){ int kk=i/C4, c4=(i%C4)*4;
        st4(&Ws[kk][c4], ld4(W + (size_t)(k0+kk)*NOUT + c4)); }
    }
    __syncthreads();
    #pragma unroll
    for (int kk=0;kk<16;kk++){
      float a0,a1,a2,a3;
      { const float4 av = *(const float4*)&As[kk][ty*4]; a0=av.x;a1=av.y;a2=av.z;a3=av.w; }
      float b[CN];
      if constexpr ((CN & 3) == 0) {
        #pragma unroll
        for (int j4=0;j4<CN;j4+=4){
          const float4 bv = *(const float4*)&Ws[kk][tx*CN+j4];
          b[j4]=bv.x;b[j4+1]=bv.y;b[j4+2]=bv.z;b[j4+3]=bv.w; }
      } else {
        #pragma unroll
        for (int j=0;j<CN;j++) b[j]=Ws[kk][tx*CN+j];
      }
      #pragma unroll
      for (int j=0;j<CN;j++){
        acc[0][j]=fmaf(a0,b[j],acc[0][j]);
        acc[1][j]=fmaf(a1,b[j],acc[1][j]);
        acc[2][j]=fmaf(a2,b[j],acc[2][j]);
        acc[3][j]=fmaf(a3,b[j],acc[3][j]);
      }
    }
    __syncthreads();
  }

  float sc[CN], sh[CN];
  if constexpr (EM==EM_BNLK) {
    const float r_ = rsqrtf(1.f + 1e-5f);
    #pragma unroll
    for (int j=0;j<CN;j++){ int c=tx*CN+j; sc[j]=bng[c]*r_; sh[j]=bias[c]; }
  }
  #pragma unroll
  for (int i=0;i<4;i++){
    const int r  = row0 + ty*4+i;
    if (r >= M) continue;
    #pragma unroll
    for (int j=0;j<CN;j++){
      const int c = tx*CN+j;
      float v = acc[i][j];
      if constexpr (EM==EM_BRELU) v = fmaxf(v + bias[c], 0.f);
      else if constexpr (EM==EM_BNLK){ float x = fmaf(v, sc[j], sh[j]); v = (x>0.f)? x : 0.2f*x; }
      C[(size_t)r*NOUT + c] = v;
    }
  }
}

// ---------------------------------------------------------------------------
// CSR build: histogram -> scan -> fill
// ---------------------------------------------------------------------------
__global__ void k_hist(const int* __restrict__ eidx, int* cntS, int* cntD, int E){
  int e = blockIdx.x*256+threadIdx.x; if (e>=E) return;
  atomicAdd(&cntS[eidx[2*e]], 1);
  atomicAdd(&cntD[eidx[2*e+1]], 1);
}
__global__ void k_scan_sum(const int* __restrict__ cnt, int* bsum, int n){
  __shared__ int red[256];
  const int b=blockIdx.x, t=threadIdx.x;
  int s=0;
  for (int i=b*1024+t; i<n && i<(b+1)*1024; i+=256) s += cnt[i];
  red[t]=s; __syncthreads();
  for (int o=128;o;o>>=1){ if(t<o) red[t]+=red[t+o]; __syncthreads(); }
  if (t==0) bsum[b]=red[0];
}
__global__ void k_scan_top(int* bsum, int nb){
  __shared__ int sh[256];
  const int t=threadIdx.x;
  int v=(t<nb)?bsum[t]:0;
  sh[t]=v; __syncthreads();
  for (int o=1;o<256;o<<=1){
    int u=0; if(t>=o) u=sh[t-o];
    __syncthreads();
    sh[t]+=u;
    __syncthreads();
  }
  if (t<nb) bsum[t]=sh[t]-v;
}
__global__ void k_scan_out(const int* __restrict__ cnt, const int* __restrict__ bofs,
                           int* __restrict__ off, int n){
  __shared__ int sh[256];
  const int b=blockIdx.x, t=threadIdx.x;
  const int base=b*1024+t*4;
  int c0=0,c1=0,c2=0,c3=0;
  if(base+0<n)c0=cnt[base+0];
  if(base+1<n)c1=cnt[base+1];
  if(base+2<n)c2=cnt[base+2];
  if(base+3<n)c3=cnt[base+3];
  int s=c0+c1+c2+c3;
  sh[t]=s; __syncthreads();
  int v=s;
  for (int o=1;o<256;o<<=1){
    int u=0; if(t>=o) u=sh[t-o];
    __syncthreads();
    sh[t]+=u;
    __syncthreads();
  }
  const int tofs = sh[t]-v + bofs[b];
  if(base+0<n) off[base+0]=tofs;
  if(base+1<n) off[base+1]=tofs+c0;
  if(base+2<n) off[base+2]=tofs+c0+c1;
  if(base+3<n) off[base+3]=tofs+c0+c1+c2;
}
__global__ void k_copyoff(const int* __restrict__ off, int* __restrict__ cur, int n){
  int i=blockIdx.x*256+threadIdx.x;
  if (i<n) cur[i]=off[i];
}
__global__ void k_setend(int* offS, int* offD, int n, int E){
  if (threadIdx.x==0 && blockIdx.x==0){ offS[n]=E; offD[n]=E; }
}
__global__ void k_fill(const int* __restrict__ eidx, int* curS, int* curD,
                       int* __restrict__ csrS, int* __restrict__ csrD, int E){
  int e=blockIdx.x*256+threadIdx.x; if (e>=E) return;
  const int s=eidx[2*e], d=eidx[2*e+1];
  csrS[atomicAdd(&curS[s],1)] = d;
  csrD[atomicAdd(&curD[d],1)] = s;
}
__global__ void k_dis(const int* __restrict__ cntD, float* __restrict__ dis, int n){
  int i=blockIdx.x*256+threadIdx.x; if(i>=n)return;
  dis[i]=rsqrtf((float)cntD[i]+1.f);
}

// ---------------------------------------------------------------------------
// Wcat = [Wbot | Wd | gcn1W]  (128 x 192 fp32)
// ---------------------------------------------------------------------------
__global__ void k_wprep(const float* __restrict__ eattnW, const float* __restrict__ gcn1W,
                        float* __restrict__ Wcat){
  int idx=blockIdx.x*256+threadIdx.x; if (idx>=128*192) return;
  int k=idx/192, c=idx-k*192;
  float v;
  if (c<64)       v = eattnW[(size_t)(128+k)*64 + c];
  else if (c<128) v = eattnW[(size_t)k*64 + (c-64)] - eattnW[(size_t)(128+k)*64 + (c-64)];
  else            v = gcn1W[(size_t)k*64 + (c-128)];
  Wcat[idx]=v;
}

// ---------------------------------------------------------------------------
// CSR gather-sum
// ---------------------------------------------------------------------------
template<int NC>
__global__ void k_gather(const float* __restrict__ src, int stride, int colbase,
                         const int* __restrict__ off, const int* __restrict__ csr,
                         float* __restrict__ out, int n){
  constexpr int TPN = NC/4;
  const int t=threadIdx.x;
  const int node = blockIdx.x*(256/TPN) + t/TPN; if (node>=n) return;
  const int cq = (t%TPN)*4;
  const int j1=off[node+1];
  float4 acc = make_float4(0.f,0.f,0.f,0.f);
  for (int j=off[node]; j<j1; ++j){
    const float4 v = ld4(src + (size_t)csr[j]*stride + colbase + cq);
    acc.x+=v.x; acc.y+=v.y; acc.z+=v.z; acc.w+=v.w;
  }
  st4(out + (size_t)node*NC + cq, acc);
}

// aei = sigmoid(row*col)
__global__ void k_aei3(const float* __restrict__ TUL, const float* __restrict__ Q,
                       const float* __restrict__ S, const int* __restrict__ cntS,
                       const int* __restrict__ cntD, const float* __restrict__ bias,
                       float* __restrict__ aei, int n){
  int idx=blockIdx.x*256+threadIdx.x; if (idx>=n*16) return;
  const int i=idx>>4, cq=(idx&15)*4;
  const float cS=(float)cntS[i], cD=(float)cntD[i];
  const float iS=1.f/fmaxf(cS,1.f), iD=1.f/fmaxf(cD,1.f);
  const float* tul = TUL + (size_t)i*192;
  const float4 T4=ld4(tul+cq), U4=ld4(tul+64+cq);
  const float4 Q4=ld4(Q+(size_t)i*64+cq), S4=ld4(S+(size_t)i*64+cq), b4=ld4(bias+cq);
  float4 o;
  o.x=sigm(((cS*(U4.x+b4.x)+Q4.x)*iS) * ((cD*(T4.x+b4.x)+S4.x)*iD));
  o.y=sigm(((cS*(U4.y+b4.y)+Q4.y)*iS) * ((cD*(T4.y+b4.y)+S4.y)*iD));
  o.z=sigm(((cS*(U4.z+b4.z)+Q4.z)*iS) * ((cD*(T4.z+b4.z)+S4.z)*iD));
  o.w=sigm(((cS*(U4.w+b4.w)+Q4.w)*iS) * ((cD*(T4.w+b4.w)+S4.w)*iD));
  st4(aei + (size_t)i*64 + cq, o);
}

// GCN aggregate + combine
template<int NC, bool AEI>
__global__ void k_gcnagg(const float* __restrict__ lin, int stride, int colbase,
                         const int* __restrict__ off, const int* __restrict__ csr,
                         const float* __restrict__ dis, const float* __restrict__ aei,
                         const float* __restrict__ bias, float* __restrict__ h, int n){
  constexpr int TPN = NC/4;
  const int t=threadIdx.x;
  const int node = blockIdx.x*(256/TPN) + t/TPN; if (node>=n) return;
  const int cq = (t%TPN)*4;
  const int j1=off[node+1];
  float4 acc = make_float4(0.f,0.f,0.f,0.f);
  for (int j=off[node]; j<j1; ++j){
    const int s=csr[j];
    const float w=dis[s];
    const float4 v = ld4(lin + (size_t)s*stride + colbase + cq);
    acc.x=fmaf(v.x,w,acc.x); acc.y=fmaf(v.y,w,acc.y);
    acc.z=fmaf(v.z,w,acc.z); acc.w=fmaf(v.w,w,acc.w);
  }
  const float dn=dis[node], d2=dn*dn;
  const float4 own=ld4(lin + (size_t)node*stride + colbase + cq), b4=ld4(bias+cq);
  float4 o;
  o.x=fmaxf(fmaf(acc.x,dn,fmaf(own.x,d2,b4.x)),0.f);
  o.y=fmaxf(fmaf(acc.y,dn,fmaf(own.y,d2,b4.y)),0.f);
  o.z=fmaxf(fmaf(acc.z,dn,fmaf(own.z,d2,b4.z)),0.f);
  o.w=fmaxf(fmaf(acc.w,dn,fmaf(own.w,d2,b4.w)),0.f);
  if (AEI){ const float4 m=ld4(aei+(size_t)node*NC+cq); o.x*=m.x;o.y*=m.y;o.z*=m.z;o.w*=m.w; }
  st4(h + (size_t)node*NC + cq, o);
}

// ---------------------------------------------------------------------------
// Generic weight transpose + cast: Wt[NP][K] bf16,
// Wt[n][k] = (Wa - Wb?)[((k+krot)%K)+rowoff][n]
// ---------------------------------------------------------------------------
__global__ void k_twtg(const float* __restrict__ Wa, const float* __restrict__ Wb,
                       short* __restrict__ Wt, int K, int N, int NP, int rowoff, int krot){
  int idx = blockIdx.x*256 + threadIdx.x;
  if (idx >= NP*K) return;
  int nn = idx / K, k = idx - nn*K;
  int ks = k + krot; if (ks >= K) ks -= K;
  float v = 0.f;
  if (nn < N){
    v = Wa[(size_t)(ks+rowoff)*N + nn];
    if (Wb) v -= Wb[(size_t)(ks+rowoff)*N + nn];
  }
  Wt[idx] = f2b(v);
}

// ---------------------------------------------------------------------------
// 64-row 32x32x16 MFMA phase, FULL-PHASE WEIGHT PRELOAD (8 steps, K=128):
// all 8 weight fragments loaded to regs BEFORE the loop, so only the first
// barrier pays vmem-drain latency; the other 15 barrier-drains are free.
// C(64 x NCOLTOT) += As(64 x 128 bf16 @ kbase) @ Wt^T  (KSTRIDE = col stride).
// 256 thr / 4 waves: wave w -> row-half (w>>1), col-half (w&1).
// A row = lane&31, k = (lane>>5)*8+j (same k-map as B -> perm-invariant).
// ---------------------------------------------------------------------------
template<int KSTRIDE, int NCOLTOT>
__device__ __forceinline__ void mm32(
    const short* __restrict__ Wt, int kbase,
    short (*As)[258], short (*Bs)[28],
    int t, int lane, int w, f32x16* acc)
{
  constexpr int NT = (NCOLTOT>=64)? NCOLTOT/64 : 1;
  const int lane31 = lane & 31, kh = lane >> 5;
  const int arow = (w>>1)*32 + lane31;
  const int colbase = (NCOLTOT>=64)? (w&1)*(NCOLTOT/2) : 0;
  const bool act = (t < NCOLTOT*2);
  const int col = t >> 1, half = t & 1;
  const short* wp = Wt + (size_t)col*KSTRIDE + half*8;
  float4 r[8];
  if (act){
    #pragma unroll
    for (int ks=0; ks<8; ++ks) r[ks] = *(const float4*)(wp + ks*16);
  }
  #pragma unroll
  for (int ks=0; ks<8; ++ks){
    if (act) *(float4*)&Bs[col][half*8] = r[ks];
    __syncthreads();
    const bf16x8 a = *(const bf16x8*)&As[arow][kbase + ks*16 + kh*8];
    #pragma unroll
    for (int ct=0; ct<NT; ++ct){
      const bf16x8 b = *(const bf16x8*)&Bs[colbase + ct*32 + lane31][kh*8];
      acc[ct] = __builtin_amdgcn_mfma_f32_32x32x16_bf16(a, b, acc[ct], 0, 0, 0);
    }
    __syncthreads();
  }
}

// C-row within 32-row tile for accumulator register `reg` (m74/m101 layout)
__device__ __forceinline__ int rowof(int reg, int kh){
  return (reg & 3) + ((reg >> 2) << 3) + (kh << 2);
}

// ---------------------------------------------------------------------------
// k_pa: per-node precompute (bf16 MFMA, 64-row tiles, coalesced stores):
//   PAs[n] = [P1 | A1] = [niB@Wtop(nred) | nf@(W1top-W1bot)]  (bf16)
//   PAd[n] = [P2 | A2] = [niB@Wbot(nred) | nf@W1bot]          (bf16)
// ---------------------------------------------------------------------------
__global__ __launch_bounds__(256) void k_pa(
  const float* __restrict__ niB, const float* __restrict__ nf,
  const short* __restrict__ wt_p1, const short* __restrict__ wt_p2,
  const short* __restrict__ wt_a1, const short* __restrict__ wt_a2,
  short* __restrict__ PAs, short* __restrict__ PAd, int n)
{
  __shared__ short As[64][258];    // 33024 B
  __shared__ short Out[64][136];   // 17408 B
  __shared__ short Bs[128][28];    //  7168 B  -> 57600 total
  const int t = threadIdx.x, lane = t & 63, w = t >> 6;
  const int lane31 = lane & 31, kh = lane >> 5;
  const int n0 = blockIdx.x * 64;
  const int srow = t >> 2, q = t & 3;
  const int grow = n0 + srow;

#define STAGE_SRC(SRC)                                                       \
  {                                                                          \
    short* dst = &As[srow][q*32];                                            \
    if (grow < n){                                                           \
      const float* src = (SRC) + (size_t)grow*128 + q*32;                    \
      _Pragma("unroll")                                                      \
      for (int p=0;p<4;p++){                                                 \
        float4 u=ld4(src+p*8), v=ld4(src+p*8+4);                             \
        bf16x8 o;                                                            \
        o[0]=f2b(u.x);o[1]=f2b(u.y);o[2]=f2b(u.z);o[3]=f2b(u.w);             \
        o[4]=f2b(v.x);o[5]=f2b(v.y);o[6]=f2b(v.z);o[7]=f2b(v.w);             \
        *(bf16x8*)(dst+p*8)=o;                                               \
      }                                                                      \
    } else {                                                                 \
      _Pragma("unroll")                                                      \
      for (int p=0;p<4;p++) *(bf16x8*)(dst+p*8) = (bf16x8)0;                 \
    }                                                                        \
  }

#define OUT_AND_STORE(DST, CB)                                               \
  {                                                                          \
    const int colbase = (w&1)*64;                                            \
    _Pragma("unroll")                                                        \
    for (int ct=0;ct<2;ct++){                                                \
      _Pragma("unroll")                                                      \
      for (int reg=0;reg<16;reg++)                                           \
        Out[(w>>1)*32 + rowof(reg,kh)][colbase + ct*32 + lane31] =           \
            f2b(acc[ct][reg]);                                               \
    }                                                                        \
    __syncthreads();                                                         \
    if (grow < n){                                                           \
      const float* srcp = (const float*)&Out[srow][q*32];                    \
      float* dstp = (float*)((DST) + (size_t)grow*256 + (CB) + q*32);        \
      _Pragma("unroll")                                                      \
      for (int p=0;p<4;p++) st4(dstp + p*4, ld4(srcp + p*4));                \
    }                                                                        \
    __syncthreads();                                                         \
  }

  f32x16 acc[2];
  // phase A: niB -> P1, P2
  STAGE_SRC(niB);
  acc[0]=(f32x16)(0.f); acc[1]=(f32x16)(0.f);
  mm32<128,128>(wt_p1, 0, As, Bs, t, lane, w, acc);
  OUT_AND_STORE(PAs, 0);
  acc[0]=(f32x16)(0.f); acc[1]=(f32x16)(0.f);
  mm32<128,128>(wt_p2, 0, As, Bs, t, lane, w, acc);
  OUT_AND_STORE(PAd, 0);
  // phase B: nf -> A1, A2
  STAGE_SRC(nf);
  acc[0]=(f32x16)(0.f); acc[1]=(f32x16)(0.f);
  mm32<128,128>(wt_a1, 0, As, Bs, t, lane, w, acc);
  OUT_AND_STORE(PAs, 128);
  acc[0]=(f32x16)(0.f); acc[1]=(f32x16)(0.f);
  mm32<128,128>(wt_a2, 0, As, Bs, t, lane, w, acc);
  OUT_AND_STORE(PAd, 128);
#undef STAGE_SRC
#undef OUT_AND_STORE
}

// ---------------------------------------------------------------------------
// Fused edge kernel (bf16 MFMA 32x32x16, 256 thr, 64 edges/block, 40KB LDS):
//   ef1 = relu(A1[s]+A2[d]+b1)*sigm(P1[s]+P2[d]+bg)  [elementwise staging]
//   emlp2 + elin1(BN,leaky) + elin2 -> elog
// ---------------------------------------------------------------------------
__global__ __launch_bounds__(256) void k_edge(
  const short* __restrict__ PAs, const short* __restrict__ PAd,
  const int* __restrict__ eidx,
  const float* __restrict__ nredb, const float* __restrict__ e1b,
  const short* __restrict__ wt_e2, const float* __restrict__ e2b,
  const short* __restrict__ wt_l1, const float* __restrict__ ebng, const float* __restrict__ ebnb,
  const short* __restrict__ wt_l2,
  float* __restrict__ elog)
{
  __shared__ short As[64][258];    // 33024 B
  __shared__ short Bs[128][28];    //  7168 B -> 40192 total (4 blocks/CU)
  const int t = threadIdx.x, lane = t & 63, w = t >> 6;
  const int lane31 = lane & 31, kh = lane >> 5;
  const int row0 = blockIdx.x * 64;

  // ---- staging: gather + elementwise gate/emlp1 -> ef1 in As cols 0..127
  {
    const int srow = t >> 2, q = t & 3;
    const int e = row0 + srow;
    const int s = eidx[2*e], d = eidx[2*e+1];
    const short* ps = PAs + (size_t)s*256;
    const short* pd = PAd + (size_t)d*256;
    #pragma unroll
    for (int c0=0;c0<32;c0+=8){
      const int c = q*32 + c0;
      const bf16x8 p1 = *(const bf16x8*)(ps + c);
      const bf16x8 p2 = *(const bf16x8*)(pd + c);
      const bf16x8 a1 = *(const bf16x8*)(ps + 128 + c);
      const bf16x8 a2 = *(const bf16x8*)(pd + 128 + c);
      const float4 bg0=ld4(nredb+c), bg1=ld4(nredb+c+4);
      const float4 be0=ld4(e1b+c),   be1=ld4(e1b+c+4);
      const float bg[8]={bg0.x,bg0.y,bg0.z,bg0.w,bg1.x,bg1.y,bg1.z,bg1.w};
      const float be[8]={be0.x,be0.y,be0.z,be0.w,be1.x,be1.y,be1.z,be1.w};
      bf16x8 o;
      #pragma unroll
      for (int j=0;j<8;j++){
        const float g = sigm(b2f(p1[j]) + b2f(p2[j]) + bg[j]);
        const float v = fmaxf(b2f(a1[j]) + b2f(a2[j]) + be[j], 0.f) * g;
        o[j] = f2b(v);
      }
      *(bf16x8*)&As[srow][c] = o;
    }
  }

  f32x16 acc[2];
  // ---- emlp2 half 0: ef2 cols 0..127 -> As cols 128..255
  acc[0]=(f32x16)(0.f); acc[1]=(f32x16)(0.f);
  mm32<128,128>(wt_e2, 0, As, Bs, t, lane, w, acc);
  #pragma unroll
  for (int ct=0;ct<2;ct++){
    const int col = (w&1)*64 + ct*32 + lane31;
    const float bb = e2b[col];
    #pragma unroll
    for (int reg=0;reg<16;reg++)
      As[(w>>1)*32 + rowof(reg,kh)][128+col] = f2b(fmaxf(acc[ct][reg] + bb, 0.f));
  }
  // ---- emlp2 half 1: ef2 cols 128..255 -> As cols 0..127 (over ef1)
  acc[0]=(f32x16)(0.f); acc[1]=(f32x16)(0.f);
  mm32<128,128>(wt_e2 + (size_t)128*128, 0, As, Bs, t, lane, w, acc);
  #pragma unroll
  for (int ct=0;ct<2;ct++){
    const int col = (w&1)*64 + ct*32 + lane31;
    const float bb = e2b[128+col];
    #pragma unroll
    for (int reg=0;reg<16;reg++)
      As[(w>>1)*32 + rowof(reg,kh)][col] = f2b(fmaxf(acc[ct][reg] + bb, 0.f));
  }

  // ---- elin1 (256 -> 128) in two K=128 halves (acc carries across calls);
  //      weights k-rotated by 128 at prep time to match As ping-pong layout
  acc[0]=(f32x16)(0.f); acc[1]=(f32x16)(0.f);
  mm32<256,128>(wt_l1,       0,   As, Bs, t, lane, w, acc);
  mm32<256,128>(wt_l1 + 128, 128, As, Bs, t, lane, w, acc);
  {
    const float r_ = rsqrtf(1.f + 1e-5f);
    #pragma unroll
    for (int ct=0;ct<2;ct++){
      const int col = (w&1)*64 + ct*32 + lane31;
      const float sc = ebng[col]*r_, sh = ebnb[col];
      #pragma unroll
      for (int reg=0;reg<16;reg++){
        const float x = fmaf(acc[ct][reg], sc, sh);
        As[(w>>1)*32 + rowof(reg,kh)][col] = f2b((x>0.f)? x : 0.2f*x);
      }
    }
  }

  // ---- elin2 (128 -> 27, padded 32); all waves compute same 32 cols
  f32x16 acc5 = (f32x16)(0.f);
  mm32<128,32>(wt_l2, 0, As, Bs, t, lane, w, &acc5);

  float* Lb = (float*)&As[0][0];   // [64][28] fp32
  if ((w&1)==0 && lane31 < 27){
    #pragma unroll
    for (int reg=0;reg<16;reg++)
      Lb[((w>>1)*32 + rowof(reg,kh))*28 + lane31] = acc5[reg];
  }
  __syncthreads();
  for (int i=t; i<64*27; i+=256){
    int rr = i/27, cc = i - rr*27;
    elog[(size_t)(row0+rr)*27 + cc] = Lb[rr*28 + cc];
  }
}

// ---------------------------- tail kernels --------------------------------
__global__ __launch_bounds__(256) void k_softmax_row(float* __restrict__ x, int M){
  const int wave = threadIdx.x>>6, lane = threadIdx.x&63;
  const int r = blockIdx.x*4 + wave; if (r>=M) return;
  float* p = x + (size_t)r*160;
  float v0 = p[lane], v1 = p[64+lane];
  float v2 = (lane<32)? p[128+lane] : -3.4e38f;
  float m = fmaxf(fmaxf(v0,v1),v2);
  for (int o=32;o;o>>=1) m = fmaxf(m, __shfl_xor(m,o));
  float e0=expf(v0-m), e1=expf(v1-m), e2=(lane<32)?expf(v2-m):0.f;
  float s=e0+e1+e2;
  for (int o=32;o;o>>=1) s += __shfl_xor(s,o);
  float inv = 1.f/s;
  p[lane]=e0*inv; p[64+lane]=e1*inv; if(lane<32)p[128+lane]=e2*inv;
}
__global__ void k_colmax(const float* __restrict__ x, uint32* __restrict__ cmax_u, int E){
  __shared__ float red[8][32];
  const int t=threadIdx.x, col=t&31, seg=t>>5;
  float m = -3.4e38f;
  if (col < 27)
    for (int r = blockIdx.x*8 + seg; r < E; r += gridDim.x*8)
      m = fmaxf(m, x[(size_t)r*27+col]);
  red[seg][col]=m; __syncthreads();
  if (t<32){
    float mm=red[0][t];
    #pragma unroll
    for (int s2=1;s2<8;s2++) mm=fmaxf(mm,red[s2][t]);
    if (t<27){
      uint32 u=__float_as_uint(mm);
      u = (u&0x80000000u)? ~u : (u|0x80000000u);
      atomicMax(&cmax_u[t], u);
    }
  }
}
__global__ void k_colfix(const uint32* __restrict__ cmax_u, float* __restrict__ cmaxf){
  int t=threadIdx.x; if (t>=27) return;
  uint32 u=cmax_u[t];
  cmaxf[t] = (u&0x80000000u)? __uint_as_float(u&0x7FFFFFFFu) : __uint_as_float(~u);
}
__global__ void k_colsum(const float* __restrict__ x, const float* __restrict__ cmaxf,
                         float* __restrict__ csum, int E){
  __shared__ float red[8][32];
  const int t=threadIdx.x, col=t&31, seg=t>>5;
  float s = 0.f;
  if (col < 27){
    const float cm = cmaxf[col];
    for (int r = blockIdx.x*8 + seg; r < E; r += gridDim.x*8)
      s += expf(x[(size_t)r*27+col] - cm);
  }
  red[seg][col]=s; __syncthreads();
  if (t<32){
    float ss=red[0][t];
    #pragma unroll
    for (int s2=1;s2<8;s2++) ss+=red[s2][t];
    if (t<27) atomicAdd(&csum[t], ss);
  }
}
__global__ void k_colnorm(float* __restrict__ x, const float* __restrict__ cmaxf,
                          const float* __restrict__ csum, int E){
  int idx=blockIdx.x*256+threadIdx.x;
  if (idx >= E*27) return;
  int c = idx - (idx/27)*27;
  x[idx] = expf(x[idx]-cmaxf[c]) / csum[c];
}

// ---------------------------------------------------------------------------
extern "C" void kernel_launch(void* const* d_in, const int* in_sizes, int n_in,
                              void* d_out, int out_size, void* d_ws, size_t ws_size,
                              hipStream_t stream)
{
  const float* nf     = (const float*)d_in[0];
  const int*   eidx   = (const int*)  d_in[1];
  const float* gcn1W  = (const float*)d_in[2];
  const float* gcn1b  = (const float*)d_in[3];
  const float* gcn2W  = (const float*)d_in[4];
  const float* gcn2b  = (const float*)d_in[5];
  const float* eattnW = (const float*)d_in[6];
  const float* eattnb = (const float*)d_in[7];
  const float* nattnW = (const float*)d_in[8];
  const float* nattnb = (const float*)d_in[9];
  const float* nredW  = (const float*)d_in[10];
  const float* nredb  = (const float*)d_in[11];
  const float* emlp1W = (const float*)d_in[12];
  const float* emlp1b = (const float*)d_in[13];
  const float* emlp2W = (const float*)d_in[14];
  const float* emlp2b = (const float*)d_in[15];
  const float* nlin1W = (const float*)d_in[16];
  const float* nbng   = (const float*)d_in[17];
  const float* nbnb   = (const float*)d_in[18];
  const float* nlin2W = (const float*)d_in[19];
  const float* elin1W = (const float*)d_in[20];
  const float* ebng   = (const float*)d_in[21];
  const float* ebnb   = (const float*)d_in[22];
  const float* elin2W = (const float*)d_in[23];
  (void)in_sizes; (void)n_in; (void)out_size; (void)ws_size;

  const int N = NN, E = EE;
  float* out  = (float*)d_out;
  float* nlog = out;                       // N*160
  float* elog = out + (size_t)N*160;       // E*27

  // ---- workspace plan (~237 MB, PAs/PAd overlay TUL+h1) ----
  float* ws   = (float*)d_ws;
  float* h2   = ws;                        // N*128
  float* lin2 = ws + (size_t)N*128;        // N*128 ; Q/S early, niB/nx later
  float* Q    = lin2;                      // N*64
  float* S    = lin2 + (size_t)N*64;       // N*64
  float* niB  = lin2;
  float* nx   = lin2;
  float* TUL  = ws + (size_t)N*256;        // N*192  [T|U|lin1]  (dead before k_pa)
  float* h1   = ws + (size_t)N*448;        // N*64              (dead before k_pa)
  short* PAs  = (short*)TUL;               // N*256 bf16
  short* PAd  = PAs + (size_t)N*256;       // N*256 bf16
  float* aei  = ws + (size_t)N*512;        // N*64
  float* dis  = ws + (size_t)N*576;        // N
  float* smalls = ws + (size_t)N*577;      // 96
  float* Wcat = smalls + 128;              // 128*192
  int*   ip   = (int*)(Wcat + 24576);
  int* cntS = ip;                          // N
  int* cntD = ip + N;                      // N
  int* offS = ip + 2*N;                    // N+64
  int* offD = ip + 3*N + 64;               // N+64
  int* curS = ip + 4*N + 128;              // N
  int* curD = ip + 5*N + 128;              // N
  int* csrS = ip + 6*N + 128;              // E
  int* csrD = ip + 6*N + 128 + E;          // E
  int* bsum = ip + 6*N + 128 + 2*E;        // 256
  short* wtb  = (short*)(bsum + 256);
  short* wt_p1 = wtb;                      // 128*128
  short* wt_p2 = wtb + 16384;              // 128*128
  short* wt_a1 = wtb + 32768;              // 128*128
  short* wt_a2 = wtb + 49152;              // 128*128
  short* wt_e2 = wtb + 65536;              // 256*128
  short* wt_l1 = wtb + 98304;              // 128*256
  short* wt_l2 = wtb + 131072;             // 32*128

  const int NB1024 = (N + 1023)/1024;      // 98

  // 0. weight prep
  k_twtg<<<64, 256,0,stream>>>(nredW,  nullptr, wt_p1, 128,128,128, 0,   0);
  k_twtg<<<64, 256,0,stream>>>(nredW,  nullptr, wt_p2, 128,128,128, 128, 0);
  k_twtg<<<64, 256,0,stream>>>(emlp1W, emlp1W+(size_t)128*128, wt_a1, 128,128,128, 0, 0);
  k_twtg<<<64, 256,0,stream>>>(emlp1W, nullptr, wt_a2, 128,128,128, 128, 0);
  k_twtg<<<128,256,0,stream>>>(emlp2W, nullptr, wt_e2, 128,256,256, 0,   0);
  k_twtg<<<128,256,0,stream>>>(elin1W, nullptr, wt_l1, 256,128,128, 0, 128);
  k_twtg<<<16, 256,0,stream>>>(elin2W, nullptr, wt_l2, 128,27, 32,  0,   0);
  k_wprep<<<96,256,0,stream>>>(eattnW, gcn1W, Wcat);

  // 1. CSR build (both directions)
  (void)hipMemsetAsync(cntS, 0, 2*(size_t)N*sizeof(int), stream);
  k_hist<<<(E+255)/256,256,0,stream>>>(eidx, cntS, cntD, E);
  k_scan_sum<<<NB1024,256,0,stream>>>(cntS, bsum, N);
  k_scan_top<<<1,256,0,stream>>>(bsum, NB1024);
  k_scan_out<<<NB1024,256,0,stream>>>(cntS, bsum, offS, N);
  k_scan_sum<<<NB1024,256,0,stream>>>(cntD, bsum, N);
  k_scan_top<<<1,256,0,stream>>>(bsum, NB1024);
  k_scan_out<<<NB1024,256,0,stream>>>(cntD, bsum, offD, N);
  k_setend<<<1,64,0,stream>>>(offS, offD, N, E);
  k_copyoff<<<(N+255)/256,256,0,stream>>>(offS, curS, N);
  k_copyoff<<<(N+255)/256,256,0,stream>>>(offD, curD, N);
  k_fill<<<(E+255)/256,256,0,stream>>>(eidx, curS, curD, csrS, csrD, E);
  k_dis<<<(N+255)/256,256,0,stream>>>(cntD, dis, N);

  // 2. TUL = nf @ [Wbot|Wd|gcn1W]
  gemm_k<128,192,EM_STORE><<<(N+63)/64,256,0,stream>>>(nf, Wcat, nullptr, nullptr, TUL, N);

  // 3. eattn segment means via gathers
  k_gather<64><<<(N+15)/16,256,0,stream>>>(TUL, 192, 0,  offS, csrS, Q, N);
  k_gather<64><<<(N+15)/16,256,0,stream>>>(TUL, 192, 64, offD, csrD, S, N);
  k_aei3<<<(N*16+255)/256,256,0,stream>>>(TUL, Q, S, cntS, cntD, eattnb, aei, N);

  // 4. GCN conv 1
  k_gcnagg<64,true><<<(N+15)/16,256,0,stream>>>(TUL, 192, 128, offD, csrD, dis, aei, gcn1b, h1, N);

  // 5. GCN conv 2
  gemm_k<64,128,EM_STORE><<<(N+63)/64,256,0,stream>>>(h1, gcn2W, nullptr, nullptr, lin2, N);
  k_gcnagg<128,false><<<(N+7)/8,256,0,stream>>>(lin2, 128, 0, offD, csrD, dis, nullptr, gcn2b, h2, N);

  // 6. node attention
  gemm_k<128,128,EM_BRELU><<<(N+63)/64,256,0,stream>>>(h2, nattnW, nattnb, nullptr, niB, N);

  // 7. per-node gate/emlp1 halves (overwrites TUL/h1 region)
  k_pa<<<(N+63)/64,256,0,stream>>>(niB, nf, wt_p1, wt_p2, wt_a1, wt_a2, PAs, PAd, N);

  // 8. fused edge chain (bf16 MFMA 32x32x16, 64-edge tiles, phase-preloaded W)
  k_edge<<<E/64,256,0,stream>>>(
      PAs, PAd, eidx,
      nredb, emlp1b, wt_e2, emlp2b,
      wt_l1, ebng, ebnb, wt_l2, elog);

  // 9. node head
  gemm_k<128,64,EM_BNLK><<<(N+63)/64,256,0,stream>>>(h2, nlin1W, nbnb, nbng, nx, N);
  gemm_k<64,160,EM_STORE><<<(N+63)/64,256,0,stream>>>(nx, nlin2W, nullptr, nullptr, nlog, N);
  k_softmax_row<<<(N+3)/4,256,0,stream>>>(nlog, N);

  // 10. column softmax over E (in place in d_out)
  (void)hipMemsetAsync(smalls, 0, 96*sizeof(float), stream);
  k_colmax<<<1024,256,0,stream>>>(elog, (uint32*)smalls, E);
  k_colfix<<<1,32,0,stream>>>((const uint32*)smalls, smalls+64);
  k_colsum<<<1024,256,0,stream>>>(elog, smalls+64, smalls+32, E);
  k_colnorm<<<(E*27+255)/256,256,0,stream>>>(elog, smalls+64, smalls+32, E);
}

// Round 13
// 1155.911 us; speedup vs baseline: 1.0034x; 1.0034x over previous
//
#include <hip/hip_runtime.h>

#define NN 100000
#define EE 320000

typedef unsigned int uint32;
typedef __attribute__((ext_vector_type(8))) short bf16x8;
typedef __attribute__((ext_vector_type(4))) float f32x4;
typedef __attribute__((ext_vector_type(16))) float f32x16;

__device__ __forceinline__ float4 ld4(const float* p){ return *(const float4*)p; }
__device__ __forceinline__ void st4(float* p, const float4 v){ *(float4*)p = v; }
__device__ __forceinline__ float sigm(float x){ return 1.f/(1.f + expf(-x)); }
__device__ __forceinline__ short f2b(float f){
  union { float f; uint32 u; } v; v.f = f;
  uint32 r = (v.u + 0x7FFFu + ((v.u>>16)&1u)) >> 16;   // RNE
  return (short)r;
}
__device__ __forceinline__ float b2f(short s){
  union { uint32 u; float f; } v; v.u = ((uint32)(unsigned short)s) << 16; return v.f;
}

constexpr int EM_STORE=0, EM_BRELU=1, EM_BNLK=2;

// ---------------------------------------------------------------------------
// Generic fp32 tiled GEMM (node path): 64 rows/block, BK=16, 256 threads.
// ---------------------------------------------------------------------------
template<int K,int NOUT,int EM>
__global__ __launch_bounds__(256) void gemm_k(
    const float* __restrict__ A,
    const float* __restrict__ W, const float* __restrict__ bias,
    const float* __restrict__ bng,
    float* __restrict__ C, int M)
{
  constexpr int CN = NOUT/16;
  __shared__ float As[16][68];
  __shared__ float Ws[16][NOUT];
  const int t  = threadIdx.x;
  const int tx = t & 15, ty = t >> 4;
  const int row0 = blockIdx.x * 64;

  float acc[4][CN];
  #pragma unroll
  for (int i=0;i<4;i++)
    #pragma unroll
    for (int j=0;j<CN;j++) acc[i][j]=0.f;

  const int r_st  = t >> 2;
  const int kq_st = (t & 3) * 4;

  for (int k0=0;k0<K;k0+=16) {
    {
      float4 v = make_float4(0.f,0.f,0.f,0.f);
      const int gr = row0 + r_st;
      if (gr < M) v = ld4(A + (size_t)gr*K + k0 + kq_st);
      As[kq_st+0][r_st]=v.x; As[kq_st+1][r_st]=v.y;
      As[kq_st+2][r_st]=v.z; As[kq_st+3][r_st]=v.w;
    }
    {
      constexpr int C4 = NOUT/4;
      for (int i=t;i<16*C4;i+=256){ int kk=i/C4, c4=(i%C4)*4;
        st4(&Ws[kk][c4], ld4(W + (size_t)(k0+kk)*NOUT + c4)); }
    }
    __syncthreads();
    #pragma unroll
    for (int kk=0;kk<16;kk++){
      float a0,a1,a2,a3;
      { const float4 av = *(const float4*)&As[kk][ty*4]; a0=av.x;a1=av.y;a2=av.z;a3=av.w; }
      float b[CN];
      if constexpr ((CN & 3) == 0) {
        #pragma unroll
        for (int j4=0;j4<CN;j4+=4){
          const float4 bv = *(const float4*)&Ws[kk][tx*CN+j4];
          b[j4]=bv.x;b[j4+1]=bv.y;b[j4+2]=bv.z;b[j4+3]=bv.w; }
      } else {
        #pragma unroll
        for (int j=0;j<CN;j++) b[j]=Ws[kk][tx*CN+j];
      }
      #pragma unroll
      for (int j=0;j<CN;j++){
        acc[0][j]=fmaf(a0,b[j],acc[0][j]);
        acc[1][j]=fmaf(a1,b[j],acc[1][j]);
        acc[2][j]=fmaf(a2,b[j],acc[2][j]);
        acc[3][j]=fmaf(a3,b[j],acc[3][j]);
      }
    }
    __syncthreads();
  }

  float sc[CN], sh[CN];
  if constexpr (EM==EM_BNLK) {
    const float r_ = rsqrtf(1.f + 1e-5f);
    #pragma unroll
    for (int j=0;j<CN;j++){ int c=tx*CN+j; sc[j]=bng[c]*r_; sh[j]=bias[c]; }
  }
  #pragma unroll
  for (int i=0;i<4;i++){
    const int r  = row0 + ty*4+i;
    if (r >= M) continue;
    #pragma unroll
    for (int j=0;j<CN;j++){
      const int c = tx*CN+j;
      float v = acc[i][j];
      if constexpr (EM==EM_BRELU) v = fmaxf(v + bias[c], 0.f);
      else if constexpr (EM==EM_BNLK){ float x = fmaf(v, sc[j], sh[j]); v = (x>0.f)? x : 0.2f*x; }
      C[(size_t)r*NOUT + c] = v;
    }
  }
}

// ---------------------------------------------------------------------------
// CSR build: histogram -> scan -> fill
// ---------------------------------------------------------------------------
__global__ void k_hist(const int* __restrict__ eidx, int* cntS, int* cntD, int E){
  int e = blockIdx.x*256+threadIdx.x; if (e>=E) return;
  atomicAdd(&cntS[eidx[2*e]], 1);
  atomicAdd(&cntD[eidx[2*e+1]], 1);
}
__global__ void k_scan_sum(const int* __restrict__ cnt, int* bsum, int n){
  __shared__ int red[256];
  const int b=blockIdx.x, t=threadIdx.x;
  int s=0;
  for (int i=b*1024+t; i<n && i<(b+1)*1024; i+=256) s += cnt[i];
  red[t]=s; __syncthreads();
  for (int o=128;o;o>>=1){ if(t<o) red[t]+=red[t+o]; __syncthreads(); }
  if (t==0) bsum[b]=red[0];
}
__global__ void k_scan_top(int* bsum, int nb){
  __shared__ int sh[256];
  const int t=threadIdx.x;
  int v=(t<nb)?bsum[t]:0;
  sh[t]=v; __syncthreads();
  for (int o=1;o<256;o<<=1){
    int u=0; if(t>=o) u=sh[t-o];
    __syncthreads();
    sh[t]+=u;
    __syncthreads();
  }
  if (t<nb) bsum[t]=sh[t]-v;
}
__global__ void k_scan_out(const int* __restrict__ cnt, const int* __restrict__ bofs,
                           int* __restrict__ off, int n){
  __shared__ int sh[256];
  const int b=blockIdx.x, t=threadIdx.x;
  const int base=b*1024+t*4;
  int c0=0,c1=0,c2=0,c3=0;
  if(base+0<n)c0=cnt[base+0];
  if(base+1<n)c1=cnt[base+1];
  if(base+2<n)c2=cnt[base+2];
  if(base+3<n)c3=cnt[base+3];
  int s=c0+c1+c2+c3;
  sh[t]=s; __syncthreads();
  int v=s;
  for (int o=1;o<256;o<<=1){
    int u=0; if(t>=o) u=sh[t-o];
    __syncthreads();
    sh[t]+=u;
    __syncthreads();
  }
  const int tofs = sh[t]-v + bofs[b];
  if(base+0<n) off[base+0]=tofs;
  if(base+1<n) off[base+1]=tofs+c0;
  if(base+2<n) off[base+2]=tofs+c0+c1;
  if(base+3<n) off[base+3]=tofs+c0+c1+c2;
}
__global__ void k_copyoff(const int* __restrict__ off, int* __restrict__ cur, int n){
  int i=blockIdx.x*256+threadIdx.x;
  if (i<n) cur[i]=off[i];
}
__global__ void k_setend(int* offS, int* offD, int n, int E){
  if (threadIdx.x==0 && blockIdx.x==0){ offS[n]=E; offD[n]=E; }
}
__global__ void k_fill(const int* __restrict__ eidx, int* curS, int* curD,
                       int* __restrict__ csrS, int* __restrict__ csrD, int E){
  int e=blockIdx.x*256+threadIdx.x; if (e>=E) return;
  const int s=eidx[2*e], d=eidx[2*e+1];
  csrS[atomicAdd(&curS[s],1)] = d;
  csrD[atomicAdd(&curD[d],1)] = s;
}
__global__ void k_dis(const int* __restrict__ cntD, float* __restrict__ dis, int n){
  int i=blockIdx.x*256+threadIdx.x; if(i>=n)return;
  dis[i]=rsqrtf((float)cntD[i]+1.f);
}

// ---------------------------------------------------------------------------
// Wcat = [Wbot | Wd | gcn1W]  (128 x 192 fp32)
// ---------------------------------------------------------------------------
__global__ void k_wprep(const float* __restrict__ eattnW, const float* __restrict__ gcn1W,
                        float* __restrict__ Wcat){
  int idx=blockIdx.x*256+threadIdx.x; if (idx>=128*192) return;
  int k=idx/192, c=idx-k*192;
  float v;
  if (c<64)       v = eattnW[(size_t)(128+k)*64 + c];
  else if (c<128) v = eattnW[(size_t)k*64 + (c-64)] - eattnW[(size_t)(128+k)*64 + (c-64)];
  else            v = gcn1W[(size_t)k*64 + (c-128)];
  Wcat[idx]=v;
}

// ---------------------------------------------------------------------------
// CSR gather-sum
// ---------------------------------------------------------------------------
template<int NC>
__global__ void k_gather(const float* __restrict__ src, int stride, int colbase,
                         const int* __restrict__ off, const int* __restrict__ csr,
                         float* __restrict__ out, int n){
  constexpr int TPN = NC/4;
  const int t=threadIdx.x;
  const int node = blockIdx.x*(256/TPN) + t/TPN; if (node>=n) return;
  const int cq = (t%TPN)*4;
  const int j1=off[node+1];
  float4 acc = make_float4(0.f,0.f,0.f,0.f);
  for (int j=off[node]; j<j1; ++j){
    const float4 v = ld4(src + (size_t)csr[j]*stride + colbase + cq);
    acc.x+=v.x; acc.y+=v.y; acc.z+=v.z; acc.w+=v.w;
  }
  st4(out + (size_t)node*NC + cq, acc);
}

// aei = sigmoid(row*col)
__global__ void k_aei3(const float* __restrict__ TUL, const float* __restrict__ Q,
                       const float* __restrict__ S, const int* __restrict__ cntS,
                       const int* __restrict__ cntD, const float* __restrict__ bias,
                       float* __restrict__ aei, int n){
  int idx=blockIdx.x*256+threadIdx.x; if (idx>=n*16) return;
  const int i=idx>>4, cq=(idx&15)*4;
  const float cS=(float)cntS[i], cD=(float)cntD[i];
  const float iS=1.f/fmaxf(cS,1.f), iD=1.f/fmaxf(cD,1.f);
  const float* tul = TUL + (size_t)i*192;
  const float4 T4=ld4(tul+cq), U4=ld4(tul+64+cq);
  const float4 Q4=ld4(Q+(size_t)i*64+cq), S4=ld4(S+(size_t)i*64+cq), b4=ld4(bias+cq);
  float4 o;
  o.x=sigm(((cS*(U4.x+b4.x)+Q4.x)*iS) * ((cD*(T4.x+b4.x)+S4.x)*iD));
  o.y=sigm(((cS*(U4.y+b4.y)+Q4.y)*iS) * ((cD*(T4.y+b4.y)+S4.y)*iD));
  o.z=sigm(((cS*(U4.z+b4.z)+Q4.z)*iS) * ((cD*(T4.z+b4.z)+S4.z)*iD));
  o.w=sigm(((cS*(U4.w+b4.w)+Q4.w)*iS) * ((cD*(T4.w+b4.w)+S4.w)*iD));
  st4(aei + (size_t)i*64 + cq, o);
}

// GCN aggregate + combine
template<int NC, bool AEI>
__global__ void k_gcnagg(const float* __restrict__ lin, int stride, int colbase,
                         const int* __restrict__ off, const int* __restrict__ csr,
                         const float* __restrict__ dis, const float* __restrict__ aei,
                         const float* __restrict__ bias, float* __restrict__ h, int n){
  constexpr int TPN = NC/4;
  const int t=threadIdx.x;
  const int node = blockIdx.x*(256/TPN) + t/TPN; if (node>=n) return;
  const int cq = (t%TPN)*4;
  const int j1=off[node+1];
  float4 acc = make_float4(0.f,0.f,0.f,0.f);
  for (int j=off[node]; j<j1; ++j){
    const int s=csr[j];
    const float w=dis[s];
    const float4 v = ld4(lin + (size_t)s*stride + colbase + cq);
    acc.x=fmaf(v.x,w,acc.x); acc.y=fmaf(v.y,w,acc.y);
    acc.z=fmaf(v.z,w,acc.z); acc.w=fmaf(v.w,w,acc.w);
  }
  const float dn=dis[node], d2=dn*dn;
  const float4 own=ld4(lin + (size_t)node*stride + colbase + cq), b4=ld4(bias+cq);
  float4 o;
  o.x=fmaxf(fmaf(acc.x,dn,fmaf(own.x,d2,b4.x)),0.f);
  o.y=fmaxf(fmaf(acc.y,dn,fmaf(own.y,d2,b4.y)),0.f);
  o.z=fmaxf(fmaf(acc.z,dn,fmaf(own.z,d2,b4.z)),0.f);
  o.w=fmaxf(fmaf(acc.w,dn,fmaf(own.w,d2,b4.w)),0.f);
  if (AEI){ const float4 m=ld4(aei+(size_t)node*NC+cq); o.x*=m.x;o.y*=m.y;o.z*=m.z;o.w*=m.w; }
  st4(h + (size_t)node*NC + cq, o);
}

// ---------------------------------------------------------------------------
// Generic weight transpose + cast: Wt[NP][K] bf16,
// Wt[n][k] = (Wa - Wb?)[((k+krot)%K)+rowoff][n]
// ---------------------------------------------------------------------------
__global__ void k_twtg(const float* __restrict__ Wa, const float* __restrict__ Wb,
                       short* __restrict__ Wt, int K, int N, int NP, int rowoff, int krot){
  int idx = blockIdx.x*256 + threadIdx.x;
  if (idx >= NP*K) return;
  int nn = idx / K, k = idx - nn*K;
  int ks = k + krot; if (ks >= K) ks -= K;
  float v = 0.f;
  if (nn < N){
    v = Wa[(size_t)(ks+rowoff)*N + nn];
    if (Wb) v -= Wb[(size_t)(ks+rowoff)*N + nn];
  }
  Wt[idx] = f2b(v);
}

// ---------------------------------------------------------------------------
// 64-row 32x32x16 MFMA phase, FULL-PHASE WEIGHT PRELOAD (8 steps, K=128):
// all 8 weight fragments loaded to regs BEFORE the loop, so only the first
// barrier pays vmem-drain latency; the other 15 barrier-drains are free.
// Requires the caller kernel to have VGPR headroom (launch_bounds min-waves
// must allow >= ~100 VGPRs, else the r[8] array spills to scratch — R11).
// ---------------------------------------------------------------------------
template<int KSTRIDE, int NCOLTOT>
__device__ __forceinline__ void mm32(
    const short* __restrict__ Wt, int kbase,
    short (*As)[258], short (*Bs)[28],
    int t, int lane, int w, f32x16* acc)
{
  constexpr int NT = (NCOLTOT>=64)? NCOLTOT/64 : 1;
  const int lane31 = lane & 31, kh = lane >> 5;
  const int arow = (w>>1)*32 + lane31;
  const int colbase = (NCOLTOT>=64)? (w&1)*(NCOLTOT/2) : 0;
  const bool act = (t < NCOLTOT*2);
  const int col = t >> 1, half = t & 1;
  const short* wp = Wt + (size_t)col*KSTRIDE + half*8;
  float4 r[8];
  if (act){
    #pragma unroll
    for (int ks=0; ks<8; ++ks) r[ks] = *(const float4*)(wp + ks*16);
  }
  #pragma unroll
  for (int ks=0; ks<8; ++ks){
    if (act) *(float4*)&Bs[col][half*8] = r[ks];
    __syncthreads();
    const bf16x8 a = *(const bf16x8*)&As[arow][kbase + ks*16 + kh*8];
    #pragma unroll
    for (int ct=0; ct<NT; ++ct){
      const bf16x8 b = *(const bf16x8*)&Bs[colbase + ct*32 + lane31][kh*8];
      acc[ct] = __builtin_amdgcn_mfma_f32_32x32x16_bf16(a, b, acc[ct], 0, 0, 0);
    }
    __syncthreads();
  }
}

// C-row within 32-row tile for accumulator register `reg` (m74/m101 layout)
__device__ __forceinline__ int rowof(int reg, int kh){
  return (reg & 3) + ((reg >> 2) << 3) + (kh << 2);
}

// ---------------------------------------------------------------------------
// k_pa: per-node precompute (bf16 MFMA, 64-row tiles, coalesced stores):
//   PAs[n] = [P1 | A1] = [niB@Wtop(nred) | nf@(W1top-W1bot)]  (bf16)
//   PAd[n] = [P2 | A2] = [niB@Wbot(nred) | nf@W1bot]          (bf16)
// LDS 57.6KB -> 2 blocks/CU; launch_bounds(256,2) -> VGPR cap 256 (no spill).
// ---------------------------------------------------------------------------
__global__ __launch_bounds__(256, 2) void k_pa(
  const float* __restrict__ niB, const float* __restrict__ nf,
  const short* __restrict__ wt_p1, const short* __restrict__ wt_p2,
  const short* __restrict__ wt_a1, const short* __restrict__ wt_a2,
  short* __restrict__ PAs, short* __restrict__ PAd, int n)
{
  __shared__ short As[64][258];    // 33024 B
  __shared__ short Out[64][136];   // 17408 B
  __shared__ short Bs[128][28];    //  7168 B  -> 57600 total
  const int t = threadIdx.x, lane = t & 63, w = t >> 6;
  const int lane31 = lane & 31, kh = lane >> 5;
  const int n0 = blockIdx.x * 64;
  const int srow = t >> 2, q = t & 3;
  const int grow = n0 + srow;

#define STAGE_SRC(SRC)                                                       \
  {                                                                          \
    short* dst = &As[srow][q*32];                                            \
    if (grow < n){                                                           \
      const float* src = (SRC) + (size_t)grow*128 + q*32;                    \
      _Pragma("unroll")                                                      \
      for (int p=0;p<4;p++){                                                 \
        float4 u=ld4(src+p*8), v=ld4(src+p*8+4);                             \
        bf16x8 o;                                                            \
        o[0]=f2b(u.x);o[1]=f2b(u.y);o[2]=f2b(u.z);o[3]=f2b(u.w);             \
        o[4]=f2b(v.x);o[5]=f2b(v.y);o[6]=f2b(v.z);o[7]=f2b(v.w);             \
        *(bf16x8*)(dst+p*8)=o;                                               \
      }                                                                      \
    } else {                                                                 \
      _Pragma("unroll")                                                      \
      for (int p=0;p<4;p++) *(bf16x8*)(dst+p*8) = (bf16x8)0;                 \
    }                                                                        \
  }

#define OUT_AND_STORE(DST, CB)                                               \
  {                                                                          \
    const int colbase = (w&1)*64;                                            \
    _Pragma("unroll")                                                        \
    for (int ct=0;ct<2;ct++){                                                \
      _Pragma("unroll")                                                      \
      for (int reg=0;reg<16;reg++)                                           \
        Out[(w>>1)*32 + rowof(reg,kh)][colbase + ct*32 + lane31] =           \
            f2b(acc[ct][reg]);                                               \
    }                                                                        \
    __syncthreads();                                                         \
    if (grow < n){                                                           \
      const float* srcp = (const float*)&Out[srow][q*32];                    \
      float* dstp = (float*)((DST) + (size_t)grow*256 + (CB) + q*32);        \
      _Pragma("unroll")                                                      \
      for (int p=0;p<4;p++) st4(dstp + p*4, ld4(srcp + p*4));                \
    }                                                                        \
    __syncthreads();                                                         \
  }

  f32x16 acc[2];
  // phase A: niB -> P1, P2
  STAGE_SRC(niB);
  acc[0]=(f32x16)(0.f); acc[1]=(f32x16)(0.f);
  mm32<128,128>(wt_p1, 0, As, Bs, t, lane, w, acc);
  OUT_AND_STORE(PAs, 0);
  acc[0]=(f32x16)(0.f); acc[1]=(f32x16)(0.f);
  mm32<128,128>(wt_p2, 0, As, Bs, t, lane, w, acc);
  OUT_AND_STORE(PAd, 0);
  // phase B: nf -> A1, A2
  STAGE_SRC(nf);
  acc[0]=(f32x16)(0.f); acc[1]=(f32x16)(0.f);
  mm32<128,128>(wt_a1, 0, As, Bs, t, lane, w, acc);
  OUT_AND_STORE(PAs, 128);
  acc[0]=(f32x16)(0.f); acc[1]=(f32x16)(0.f);
  mm32<128,128>(wt_a2, 0, As, Bs, t, lane, w, acc);
  OUT_AND_STORE(PAd, 128);
#undef STAGE_SRC
#undef OUT_AND_STORE
}

// ---------------------------------------------------------------------------
// Fused edge kernel (bf16 MFMA 32x32x16, 256 thr, 64 edges/block, 40KB LDS):
//   ef1 = relu(A1[s]+A2[d]+b1)*sigm(P1[s]+P2[d]+bg)  [elementwise staging]
//   emlp2 + elin1(BN,leaky) + elin2 -> elog
// launch_bounds(256,4): 4 blocks/CU (matches 40KB LDS), VGPR cap 128 ->
// the mm32 weight preload stays in registers (R11 spill fix).
// ---------------------------------------------------------------------------
__global__ __launch_bounds__(256, 4) void k_edge(
  const short* __restrict__ PAs, const short* __restrict__ PAd,
  const int* __restrict__ eidx,
  const float* __restrict__ nredb, const float* __restrict__ e1b,
  const short* __restrict__ wt_e2, const float* __restrict__ e2b,
  const short* __restrict__ wt_l1, const float* __restrict__ ebng, const float* __restrict__ ebnb,
  const short* __restrict__ wt_l2,
  float* __restrict__ elog)
{
  __shared__ short As[64][258];    // 33024 B
  __shared__ short Bs[128][28];    //  7168 B -> 40192 total (4 blocks/CU)
  const int t = threadIdx.x, lane = t & 63, w = t >> 6;
  const int lane31 = lane & 31, kh = lane >> 5;
  const int row0 = blockIdx.x * 64;

  // ---- staging: gather + elementwise gate/emlp1 -> ef1 in As cols 0..127
  {
    const int srow = t >> 2, q = t & 3;
    const int e = row0 + srow;
    const int s = eidx[2*e], d = eidx[2*e+1];
    const short* ps = PAs + (size_t)s*256;
    const short* pd = PAd + (size_t)d*256;
    #pragma unroll
    for (int c0=0;c0<32;c0+=8){
      const int c = q*32 + c0;
      const bf16x8 p1 = *(const bf16x8*)(ps + c);
      const bf16x8 p2 = *(const bf16x8*)(pd + c);
      const bf16x8 a1 = *(const bf16x8*)(ps + 128 + c);
      const bf16x8 a2 = *(const bf16x8*)(pd + 128 + c);
      const float4 bg0=ld4(nredb+c), bg1=ld4(nredb+c+4);
      const float4 be0=ld4(e1b+c),   be1=ld4(e1b+c+4);
      const float bg[8]={bg0.x,bg0.y,bg0.z,bg0.w,bg1.x,bg1.y,bg1.z,bg1.w};
      const float be[8]={be0.x,be0.y,be0.z,be0.w,be1.x,be1.y,be1.z,be1.w};
      bf16x8 o;
      #pragma unroll
      for (int j=0;j<8;j++){
        const float g = sigm(b2f(p1[j]) + b2f(p2[j]) + bg[j]);
        const float v = fmaxf(b2f(a1[j]) + b2f(a2[j]) + be[j], 0.f) * g;
        o[j] = f2b(v);
      }
      *(bf16x8*)&As[srow][c] = o;
    }
  }

  f32x16 acc[2];
  // ---- emlp2 half 0: ef2 cols 0..127 -> As cols 128..255
  acc[0]=(f32x16)(0.f); acc[1]=(f32x16)(0.f);
  mm32<128,128>(wt_e2, 0, As, Bs, t, lane, w, acc);
  #pragma unroll
  for (int ct=0;ct<2;ct++){
    const int col = (w&1)*64 + ct*32 + lane31;
    const float bb = e2b[col];
    #pragma unroll
    for (int reg=0;reg<16;reg++)
      As[(w>>1)*32 + rowof(reg,kh)][128+col] = f2b(fmaxf(acc[ct][reg] + bb, 0.f));
  }
  // ---- emlp2 half 1: ef2 cols 128..255 -> As cols 0..127 (over ef1)
  acc[0]=(f32x16)(0.f); acc[1]=(f32x16)(0.f);
  mm32<128,128>(wt_e2 + (size_t)128*128, 0, As, Bs, t, lane, w, acc);
  #pragma unroll
  for (int ct=0;ct<2;ct++){
    const int col = (w&1)*64 + ct*32 + lane31;
    const float bb = e2b[128+col];
    #pragma unroll
    for (int reg=0;reg<16;reg++)
      As[(w>>1)*32 + rowof(reg,kh)][col] = f2b(fmaxf(acc[ct][reg] + bb, 0.f));
  }

  // ---- elin1 (256 -> 128) in two K=128 halves (acc carries across calls);
  //      weights k-rotated by 128 at prep time to match As ping-pong layout
  acc[0]=(f32x16)(0.f); acc[1]=(f32x16)(0.f);
  mm32<256,128>(wt_l1,       0,   As, Bs, t, lane, w, acc);
  mm32<256,128>(wt_l1 + 128, 128, As, Bs, t, lane, w, acc);
  {
    const float r_ = rsqrtf(1.f + 1e-5f);
    #pragma unroll
    for (int ct=0;ct<2;ct++){
      const int col = (w&1)*64 + ct*32 + lane31;
      const float sc = ebng[col]*r_, sh = ebnb[col];
      #pragma unroll
      for (int reg=0;reg<16;reg++){
        const float x = fmaf(acc[ct][reg], sc, sh);
        As[(w>>1)*32 + rowof(reg,kh)][col] = f2b((x>0.f)? x : 0.2f*x);
      }
    }
  }

  // ---- elin2 (128 -> 27, padded 32); all waves compute same 32 cols
  f32x16 acc5 = (f32x16)(0.f);
  mm32<128,32>(wt_l2, 0, As, Bs, t, lane, w, &acc5);

  float* Lb = (float*)&As[0][0];   // [64][28] fp32
  if ((w&1)==0 && lane31 < 27){
    #pragma unroll
    for (int reg=0;reg<16;reg++)
      Lb[((w>>1)*32 + rowof(reg,kh))*28 + lane31] = acc5[reg];
  }
  __syncthreads();
  for (int i=t; i<64*27; i+=256){
    int rr = i/27, cc = i - rr*27;
    elog[(size_t)(row0+rr)*27 + cc] = Lb[rr*28 + cc];
  }
}

// ---------------------------- tail kernels --------------------------------
__global__ __launch_bounds__(256) void k_softmax_row(float* __restrict__ x, int M){
  const int wave = threadIdx.x>>6, lane = threadIdx.x&63;
  const int r = blockIdx.x*4 + wave; if (r>=M) return;
  float* p = x + (size_t)r*160;
  float v0 = p[lane], v1 = p[64+lane];
  float v2 = (lane<32)? p[128+lane] : -3.4e38f;
  float m = fmaxf(fmaxf(v0,v1),v2);
  for (int o=32;o;o>>=1) m = fmaxf(m, __shfl_xor(m,o));
  float e0=expf(v0-m), e1=expf(v1-m), e2=(lane<32)?expf(v2-m):0.f;
  float s=e0+e1+e2;
  for (int o=32;o;o>>=1) s += __shfl_xor(s,o);
  float inv = 1.f/s;
  p[lane]=e0*inv; p[64+lane]=e1*inv; if(lane<32)p[128+lane]=e2*inv;
}
__global__ void k_colmax(const float* __restrict__ x, uint32* __restrict__ cmax_u, int E){
  __shared__ float red[8][32];
  const int t=threadIdx.x, col=t&31, seg=t>>5;
  float m = -3.4e38f;
  if (col < 27)
    for (int r = blockIdx.x*8 + seg; r < E; r += gridDim.x*8)
      m = fmaxf(m, x[(size_t)r*27+col]);
  red[seg][col]=m; __syncthreads();
  if (t<32){
    float mm=red[0][t];
    #pragma unroll
    for (int s2=1;s2<8;s2++) mm=fmaxf(mm,red[s2][t]);
    if (t<27){
      uint32 u=__float_as_uint(mm);
      u = (u&0x80000000u)? ~u : (u|0x80000000u);
      atomicMax(&cmax_u[t], u);
    }
  }
}
__global__ void k_colfix(const uint32* __restrict__ cmax_u, float* __restrict__ cmaxf){
  int t=threadIdx.x; if (t>=27) return;
  uint32 u=cmax_u[t];
  cmaxf[t] = (u&0x80000000u)? __uint_as_float(u&0x7FFFFFFFu) : __uint_as_float(~u);
}
__global__ void k_colsum(const float* __restrict__ x, const float* __restrict__ cmaxf,
                         float* __restrict__ csum, int E){
  __shared__ float red[8][32];
  const int t=threadIdx.x, col=t&31, seg=t>>5;
  float s = 0.f;
  if (col < 27){
    const float cm = cmaxf[col];
    for (int r = blockIdx.x*8 + seg; r < E; r += gridDim.x*8)
      s += expf(x[(size_t)r*27+col] - cm);
  }
  red[seg][col]=s; __syncthreads();
  if (t<32){
    float ss=red[0][t];
    #pragma unroll
    for (int s2=1;s2<8;s2++) ss+=red[s2][t];
    if (t<27) atomicAdd(&csum[t], ss);
  }
}
__global__ void k_colnorm(float* __restrict__ x, const float* __restrict__ cmaxf,
                          const float* __restrict__ csum, int E){
  int idx=blockIdx.x*256+threadIdx.x;
  if (idx >= E*27) return;
  int c = idx - (idx/27)*27;
  x[idx] = expf(x[idx]-cmaxf[c]) / csum[c];
}

// ---------------------------------------------------------------------------
extern "C" void kernel_launch(void* const* d_in, const int* in_sizes, int n_in,
                              void* d_out, int out_size, void* d_ws, size_t ws_size,
                              hipStream_t stream)
{
  const float* nf     = (const float*)d_in[0];
  const int*   eidx   = (const int*)  d_in[1];
  const float* gcn1W  = (const float*)d_in[2];
  const float* gcn1b  = (const float*)d_in[3];
  const float* gcn2W  = (const float*)d_in[4];
  const float* gcn2b  = (const float*)d_in[5];
  const float* eattnW = (const float*)d_in[6];
  const float* eattnb = (const float*)d_in[7];
  const float* nattnW = (const float*)d_in[8];
  const float* nattnb = (const float*)d_in[9];
  const float* nredW  = (const float*)d_in[10];
  const float* nredb  = (const float*)d_in[11];
  const float* emlp1W = (const float*)d_in[12];
  const float* emlp1b = (const float*)d_in[13];
  const float* emlp2W = (const float*)d_in[14];
  const float* emlp2b = (const float*)d_in[15];
  const float* nlin1W = (const float*)d_in[16];
  const float* nbng   = (const float*)d_in[17];
  const float* nbnb   = (const float*)d_in[18];
  const float* nlin2W = (const float*)d_in[19];
  const float* elin1W = (const float*)d_in[20];
  const float* ebng   = (const float*)d_in[21];
  const float* ebnb   = (const float*)d_in[22];
  const float* elin2W = (const float*)d_in[23];
  (void)in_sizes; (void)n_in; (void)out_size; (void)ws_size;

  const int N = NN, E = EE;
  float* out  = (float*)d_out;
  float* nlog = out;                       // N*160
  float* elog = out + (size_t)N*160;       // E*27

  // ---- workspace plan (~237 MB, PAs/PAd overlay TUL+h1) ----
  float* ws   = (float*)d_ws;
  float* h2   = ws;                        // N*128
  float* lin2 = ws + (size_t)N*128;        // N*128 ; Q/S early, niB/nx later
  float* Q    = lin2;                      // N*64
  float* S    = lin2 + (size_t)N*64;       // N*64
  float* niB  = lin2;
  float* nx   = lin2;
  float* TUL  = ws + (size_t)N*256;        // N*192  [T|U|lin1]  (dead before k_pa)
  float* h1   = ws + (size_t)N*448;        // N*64              (dead before k_pa)
  short* PAs  = (short*)TUL;               // N*256 bf16
  short* PAd  = PAs + (size_t)N*256;       // N*256 bf16
  float* aei  = ws + (size_t)N*512;        // N*64
  float* dis  = ws + (size_t)N*576;        // N
  float* smalls = ws + (size_t)N*577;      // 96
  float* Wcat = smalls + 128;              // 128*192
  int*   ip   = (int*)(Wcat + 24576);
  int* cntS = ip;                          // N
  int* cntD = ip + N;                      // N
  int* offS = ip + 2*N;                    // N+64
  int* offD = ip + 3*N + 64;               // N+64
  int* curS = ip + 4*N + 128;              // N
  int* curD = ip + 5*N + 128;              // N
  int* csrS = ip + 6*N + 128;              // E
  int* csrD = ip + 6*N + 128 + E;          // E
  int* bsum = ip + 6*N + 128 + 2*E;        // 256
  short* wtb  = (short*)(bsum + 256);
  short* wt_p1 = wtb;                      // 128*128
  short* wt_p2 = wtb + 16384;              // 128*128
  short* wt_a1 = wtb + 32768;              // 128*128
  short* wt_a2 = wtb + 49152;              // 128*128
  short* wt_e2 = wtb + 65536;              // 256*128
  short* wt_l1 = wtb + 98304;              // 128*256
  short* wt_l2 = wtb + 131072;             // 32*128

  const int NB1024 = (N + 1023)/1024;      // 98

  // 0. weight prep
  k_twtg<<<64, 256,0,stream>>>(nredW,  nullptr, wt_p1, 128,128,128, 0,   0);
  k_twtg<<<64, 256,0,stream>>>(nredW,  nullptr, wt_p2, 128,128,128, 128, 0);
  k_twtg<<<64, 256,0,stream>>>(emlp1W, emlp1W+(size_t)128*128, wt_a1, 128,128,128, 0, 0);
  k_twtg<<<64, 256,0,stream>>>(emlp1W, nullptr, wt_a2, 128,128,128, 128, 0);
  k_twtg<<<128,256,0,stream>>>(emlp2W, nullptr, wt_e2, 128,256,256, 0,   0);
  k_twtg<<<128,256,0,stream>>>(elin1W, nullptr, wt_l1, 256,128,128, 0, 128);
  k_twtg<<<16, 256,0,stream>>>(elin2W, nullptr, wt_l2, 128,27, 32,  0,   0);
  k_wprep<<<96,256,0,stream>>>(eattnW, gcn1W, Wcat);

  // 1. CSR build (both directions)
  (void)hipMemsetAsync(cntS, 0, 2*(size_t)N*sizeof(int), stream);
  k_hist<<<(E+255)/256,256,0,stream>>>(eidx, cntS, cntD, E);
  k_scan_sum<<<NB1024,256,0,stream>>>(cntS, bsum, N);
  k_scan_top<<<1,256,0,stream>>>(bsum, NB1024);
  k_scan_out<<<NB1024,256,0,stream>>>(cntS, bsum, offS, N);
  k_scan_sum<<<NB1024,256,0,stream>>>(cntD, bsum, N);
  k_scan_top<<<1,256,0,stream>>>(bsum, NB1024);
  k_scan_out<<<NB1024,256,0,stream>>>(cntD, bsum, offD, N);
  k_setend<<<1,64,0,stream>>>(offS, offD, N, E);
  k_copyoff<<<(N+255)/256,256,0,stream>>>(offS, curS, N);
  k_copyoff<<<(N+255)/256,256,0,stream>>>(offD, curD, N);
  k_fill<<<(E+255)/256,256,0,stream>>>(eidx, curS, curD, csrS, csrD, E);
  k_dis<<<(N+255)/256,256,0,stream>>>(cntD, dis, N);

  // 2. TUL = nf @ [Wbot|Wd|gcn1W]
  gemm_k<128,192,EM_STORE><<<(N+63)/64,256,0,stream>>>(nf, Wcat, nullptr, nullptr, TUL, N);

  // 3. eattn segment means via gathers
  k_gather<64><<<(N+15)/16,256,0,stream>>>(TUL, 192, 0,  offS, csrS, Q, N);
  k_gather<64><<<(N+15)/16,256,0,stream>>>(TUL, 192, 64, offD, csrD, S, N);
  k_aei3<<<(N*16+255)/256,256,0,stream>>>(TUL, Q, S, cntS, cntD, eattnb, aei, N);

  // 4. GCN conv 1
  k_gcnagg<64,true><<<(N+15)/16,256,0,stream>>>(TUL, 192, 128, offD, csrD, dis, aei, gcn1b, h1, N);

  // 5. GCN conv 2
  gemm_k<64,128,EM_STORE><<<(N+63)/64,256,0,stream>>>(h1, gcn2W, nullptr, nullptr, lin2, N);
  k_gcnagg<128,false><<<(N+7)/8,256,0,stream>>>(lin2, 128, 0, offD, csrD, dis, nullptr, gcn2b, h2, N);

  // 6. node attention
  gemm_k<128,128,EM_BRELU><<<(N+63)/64,256,0,stream>>>(h2, nattnW, nattnb, nullptr, niB, N);

  // 7. per-node gate/emlp1 halves (overwrites TUL/h1 region)
  k_pa<<<(N+63)/64,256,0,stream>>>(niB, nf, wt_p1, wt_p2, wt_a1, wt_a2, PAs, PAd, N);

  // 8. fused edge chain (bf16 MFMA 32x32x16, phase-preloaded W, no-spill)
  k_edge<<<E/64,256,0,stream>>>(
      PAs, PAd, eidx,
      nredb, emlp1b, wt_e2, emlp2b,
      wt_l1, ebng, ebnb, wt_l2, elog);

  // 9. node head
  gemm_k<128,64,EM_BNLK><<<(N+63)/64,256,0,stream>>>(h2, nlin1W, nbnb, nbng, nx, N);
  gemm_k<64,160,EM_STORE><<<(N+63)/64,256,0,stream>>>(nx, nlin2W, nullptr, nullptr, nlog, N);
  k_softmax_row<<<(N+3)/4,256,0,stream>>>(nlog, N);

  // 10. column softmax over E (in place in d_out)
  (void)hipMemsetAsync(smalls, 0, 96*sizeof(float), stream);
  k_colmax<<<1024,256,0,stream>>>(elog, (uint32*)smalls, E);
  k_colfix<<<1,32,0,stream>>>((const uint32*)smalls, smalls+64);
  k_colsum<<<1024,256,0,stream>>>(elog, smalls+64, smalls+32, E);
  k_colnorm<<<(E*27+255)/256,256,0,stream>>>(elog, smalls+64, smalls+32, E);
}

// Round 14
// 1051.541 us; speedup vs baseline: 1.1030x; 1.0993x over previous
//
#include <hip/hip_runtime.h>

#define NN 100000
#define EE 320000

typedef unsigned int uint32;
typedef __attribute__((ext_vector_type(8))) short bf16x8;
typedef __attribute__((ext_vector_type(4))) float f32x4;
typedef __attribute__((ext_vector_type(16))) float f32x16;

__device__ __forceinline__ float4 ld4(const float* p){ return *(const float4*)p; }
__device__ __forceinline__ void st4(float* p, const float4 v){ *(float4*)p = v; }
__device__ __forceinline__ float sigm(float x){ return 1.f/(1.f + expf(-x)); }
__device__ __forceinline__ short f2b(float f){
  union { float f; uint32 u; } v; v.f = f;
  uint32 r = (v.u + 0x7FFFu + ((v.u>>16)&1u)) >> 16;   // RNE
  return (short)r;
}
__device__ __forceinline__ float b2f(short s){
  union { uint32 u; float f; } v; v.u = ((uint32)(unsigned short)s) << 16; return v.f;
}

constexpr int EM_STORE=0, EM_BRELU=1, EM_BNLK=2;

// ---------------------------------------------------------------------------
// Generic fp32 tiled GEMM (node path): 64 rows/block, BK=16, 256 threads.
// ---------------------------------------------------------------------------
template<int K,int NOUT,int EM>
__global__ __launch_bounds__(256) void gemm_k(
    const float* __restrict__ A,
    const float* __restrict__ W, const float* __restrict__ bias,
    const float* __restrict__ bng,
    float* __restrict__ C, int M)
{
  constexpr int CN = NOUT/16;
  __shared__ float As[16][68];
  __shared__ float Ws[16][NOUT];
  const int t  = threadIdx.x;
  const int tx = t & 15, ty = t >> 4;
  const int row0 = blockIdx.x * 64;

  float acc[4][CN];
  #pragma unroll
  for (int i=0;i<4;i++)
    #pragma unroll
    for (int j=0;j<CN;j++) acc[i][j]=0.f;

  const int r_st  = t >> 2;
  const int kq_st = (t & 3) * 4;

  for (int k0=0;k0<K;k0+=16) {
    {
      float4 v = make_float4(0.f,0.f,0.f,0.f);
      const int gr = row0 + r_st;
      if (gr < M) v = ld4(A + (size_t)gr*K + k0 + kq_st);
      As[kq_st+0][r_st]=v.x; As[kq_st+1][r_st]=v.y;
      As[kq_st+2][r_st]=v.z; As[kq_st+3][r_st]=v.w;
    }
    {
      constexpr int C4 = NOUT/4;
      for (int i=t;i<16*C4;i+=256){ int kk=i/C4, c4=(i%C4)*4;
        st4(&Ws[kk][c4], ld4(W + (size_t)(k0+kk)*NOUT + c4)); }
    }
    __syncthreads();
    #pragma unroll
    for (int kk=0;kk<16;kk++){
      float a0,a1,a2,a3;
      { const float4 av = *(const float4*)&As[kk][ty*4]; a0=av.x;a1=av.y;a2=av.z;a3=av.w; }
      float b[CN];
      if constexpr ((CN & 3) == 0) {
        #pragma unroll
        for (int j4=0;j4<CN;j4+=4){
          const float4 bv = *(const float4*)&Ws[kk][tx*CN+j4];
          b[j4]=bv.x;b[j4+1]=bv.y;b[j4+2]=bv.z;b[j4+3]=bv.w; }
      } else {
        #pragma unroll
        for (int j=0;j<CN;j++) b[j]=Ws[kk][tx*CN+j];
      }
      #pragma unroll
      for (int j=0;j<CN;j++){
        acc[0][j]=fmaf(a0,b[j],acc[0][j]);
        acc[1][j]=fmaf(a1,b[j],acc[1][j]);
        acc[2][j]=fmaf(a2,b[j],acc[2][j]);
        acc[3][j]=fmaf(a3,b[j],acc[3][j]);
      }
    }
    __syncthreads();
  }

  float sc[CN], sh[CN];
  if constexpr (EM==EM_BNLK) {
    const float r_ = rsqrtf(1.f + 1e-5f);
    #pragma unroll
    for (int j=0;j<CN;j++){ int c=tx*CN+j; sc[j]=bng[c]*r_; sh[j]=bias[c]; }
  }
  #pragma unroll
  for (int i=0;i<4;i++){
    const int r  = row0 + ty*4+i;
    if (r >= M) continue;
    #pragma unroll
    for (int j=0;j<CN;j++){
      const int c = tx*CN+j;
      float v = acc[i][j];
      if constexpr (EM==EM_BRELU) v = fmaxf(v + bias[c], 0.f);
      else if constexpr (EM==EM_BNLK){ float x = fmaf(v, sc[j], sh[j]); v = (x>0.f)? x : 0.2f*x; }
      C[(size_t)r*NOUT + c] = v;
    }
  }
}

// ---------------------------------------------------------------------------
// CSR build: histogram -> scan -> fill
// ---------------------------------------------------------------------------
__global__ void k_hist(const int* __restrict__ eidx, int* cntS, int* cntD, int E){
  int e = blockIdx.x*256+threadIdx.x; if (e>=E) return;
  atomicAdd(&cntS[eidx[2*e]], 1);
  atomicAdd(&cntD[eidx[2*e+1]], 1);
}
__global__ void k_scan_sum(const int* __restrict__ cnt, int* bsum, int n){
  __shared__ int red[256];
  const int b=blockIdx.x, t=threadIdx.x;
  int s=0;
  for (int i=b*1024+t; i<n && i<(b+1)*1024; i+=256) s += cnt[i];
  red[t]=s; __syncthreads();
  for (int o=128;o;o>>=1){ if(t<o) red[t]+=red[t+o]; __syncthreads(); }
  if (t==0) bsum[b]=red[0];
}
__global__ void k_scan_top(int* bsum, int nb){
  __shared__ int sh[256];
  const int t=threadIdx.x;
  int v=(t<nb)?bsum[t]:0;
  sh[t]=v; __syncthreads();
  for (int o=1;o<256;o<<=1){
    int u=0; if(t>=o) u=sh[t-o];
    __syncthreads();
    sh[t]+=u;
    __syncthreads();
  }
  if (t<nb) bsum[t]=sh[t]-v;
}
__global__ void k_scan_out(const int* __restrict__ cnt, const int* __restrict__ bofs,
                           int* __restrict__ off, int n){
  __shared__ int sh[256];
  const int b=blockIdx.x, t=threadIdx.x;
  const int base=b*1024+t*4;
  int c0=0,c1=0,c2=0,c3=0;
  if(base+0<n)c0=cnt[base+0];
  if(base+1<n)c1=cnt[base+1];
  if(base+2<n)c2=cnt[base+2];
  if(base+3<n)c3=cnt[base+3];
  int s=c0+c1+c2+c3;
  sh[t]=s; __syncthreads();
  int v=s;
  for (int o=1;o<256;o<<=1){
    int u=0; if(t>=o) u=sh[t-o];
    __syncthreads();
    sh[t]+=u;
    __syncthreads();
  }
  const int tofs = sh[t]-v + bofs[b];
  if(base+0<n) off[base+0]=tofs;
  if(base+1<n) off[base+1]=tofs+c0;
  if(base+2<n) off[base+2]=tofs+c0+c1;
  if(base+3<n) off[base+3]=tofs+c0+c1+c2;
}
__global__ void k_copyoff(const int* __restrict__ off, int* __restrict__ cur, int n){
  int i=blockIdx.x*256+threadIdx.x;
  if (i<n) cur[i]=off[i];
}
__global__ void k_setend(int* offS, int* offD, int n, int E){
  if (threadIdx.x==0 && blockIdx.x==0){ offS[n]=E; offD[n]=E; }
}
__global__ void k_fill(const int* __restrict__ eidx, int* curS, int* curD,
                       int* __restrict__ csrS, int* __restrict__ csrD, int E){
  int e=blockIdx.x*256+threadIdx.x; if (e>=E) return;
  const int s=eidx[2*e], d=eidx[2*e+1];
  csrS[atomicAdd(&curS[s],1)] = d;
  csrD[atomicAdd(&curD[d],1)] = s;
}
__global__ void k_dis(const int* __restrict__ cntD, float* __restrict__ dis, int n){
  int i=blockIdx.x*256+threadIdx.x; if(i>=n)return;
  dis[i]=rsqrtf((float)cntD[i]+1.f);
}

// ---------------------------------------------------------------------------
// Wcat = [Wbot | Wd | gcn1W]  (128 x 192 fp32)
// ---------------------------------------------------------------------------
__global__ void k_wprep(const float* __restrict__ eattnW, const float* __restrict__ gcn1W,
                        float* __restrict__ Wcat){
  int idx=blockIdx.x*256+threadIdx.x; if (idx>=128*192) return;
  int k=idx/192, c=idx-k*192;
  float v;
  if (c<64)       v = eattnW[(size_t)(128+k)*64 + c];
  else if (c<128) v = eattnW[(size_t)k*64 + (c-64)] - eattnW[(size_t)(128+k)*64 + (c-64)];
  else            v = gcn1W[(size_t)k*64 + (c-128)];
  Wcat[idx]=v;
}

// ---------------------------------------------------------------------------
// CSR gather-sum
// ---------------------------------------------------------------------------
template<int NC>
__global__ void k_gather(const float* __restrict__ src, int stride, int colbase,
                         const int* __restrict__ off, const int* __restrict__ csr,
                         float* __restrict__ out, int n){
  constexpr int TPN = NC/4;
  const int t=threadIdx.x;
  const int node = blockIdx.x*(256/TPN) + t/TPN; if (node>=n) return;
  const int cq = (t%TPN)*4;
  const int j1=off[node+1];
  float4 acc = make_float4(0.f,0.f,0.f,0.f);
  for (int j=off[node]; j<j1; ++j){
    const float4 v = ld4(src + (size_t)csr[j]*stride + colbase + cq);
    acc.x+=v.x; acc.y+=v.y; acc.z+=v.z; acc.w+=v.w;
  }
  st4(out + (size_t)node*NC + cq, acc);
}

// aei = sigmoid(row*col)
__global__ void k_aei3(const float* __restrict__ TUL, const float* __restrict__ Q,
                       const float* __restrict__ S, const int* __restrict__ cntS,
                       const int* __restrict__ cntD, const float* __restrict__ bias,
                       float* __restrict__ aei, int n){
  int idx=blockIdx.x*256+threadIdx.x; if (idx>=n*16) return;
  const int i=idx>>4, cq=(idx&15)*4;
  const float cS=(float)cntS[i], cD=(float)cntD[i];
  const float iS=1.f/fmaxf(cS,1.f), iD=1.f/fmaxf(cD,1.f);
  const float* tul = TUL + (size_t)i*192;
  const float4 T4=ld4(tul+cq), U4=ld4(tul+64+cq);
  const float4 Q4=ld4(Q+(size_t)i*64+cq), S4=ld4(S+(size_t)i*64+cq), b4=ld4(bias+cq);
  float4 o;
  o.x=sigm(((cS*(U4.x+b4.x)+Q4.x)*iS) * ((cD*(T4.x+b4.x)+S4.x)*iD));
  o.y=sigm(((cS*(U4.y+b4.y)+Q4.y)*iS) * ((cD*(T4.y+b4.y)+S4.y)*iD));
  o.z=sigm(((cS*(U4.z+b4.z)+Q4.z)*iS) * ((cD*(T4.z+b4.z)+S4.z)*iD));
  o.w=sigm(((cS*(U4.w+b4.w)+Q4.w)*iS) * ((cD*(T4.w+b4.w)+S4.w)*iD));
  st4(aei + (size_t)i*64 + cq, o);
}

// GCN aggregate + combine
template<int NC, bool AEI>
__global__ void k_gcnagg(const float* __restrict__ lin, int stride, int colbase,
                         const int* __restrict__ off, const int* __restrict__ csr,
                         const float* __restrict__ dis, const float* __restrict__ aei,
                         const float* __restrict__ bias, float* __restrict__ h, int n){
  constexpr int TPN = NC/4;
  const int t=threadIdx.x;
  const int node = blockIdx.x*(256/TPN) + t/TPN; if (node>=n) return;
  const int cq = (t%TPN)*4;
  const int j1=off[node+1];
  float4 acc = make_float4(0.f,0.f,0.f,0.f);
  for (int j=off[node]; j<j1; ++j){
    const int s=csr[j];
    const float w=dis[s];
    const float4 v = ld4(lin + (size_t)s*stride + colbase + cq);
    acc.x=fmaf(v.x,w,acc.x); acc.y=fmaf(v.y,w,acc.y);
    acc.z=fmaf(v.z,w,acc.z); acc.w=fmaf(v.w,w,acc.w);
  }
  const float dn=dis[node], d2=dn*dn;
  const float4 own=ld4(lin + (size_t)node*stride + colbase + cq), b4=ld4(bias+cq);
  float4 o;
  o.x=fmaxf(fmaf(acc.x,dn,fmaf(own.x,d2,b4.x)),0.f);
  o.y=fmaxf(fmaf(acc.y,dn,fmaf(own.y,d2,b4.y)),0.f);
  o.z=fmaxf(fmaf(acc.z,dn,fmaf(own.z,d2,b4.z)),0.f);
  o.w=fmaxf(fmaf(acc.w,dn,fmaf(own.w,d2,b4.w)),0.f);
  if (AEI){ const float4 m=ld4(aei+(size_t)node*NC+cq); o.x*=m.x;o.y*=m.y;o.z*=m.z;o.w*=m.w; }
  st4(h + (size_t)node*NC + cq, o);
}

// ---------------------------------------------------------------------------
// Generic weight transpose + cast: Wt[NP][K] bf16,
// Wt[n][k] = (Wa - Wb?)[((k+krot)%K)+rowoff][n]
// ---------------------------------------------------------------------------
__global__ void k_twtg(const float* __restrict__ Wa, const float* __restrict__ Wb,
                       short* __restrict__ Wt, int K, int N, int NP, int rowoff, int krot){
  int idx = blockIdx.x*256 + threadIdx.x;
  if (idx >= NP*K) return;
  int nn = idx / K, k = idx - nn*K;
  int ks = k + krot; if (ks >= K) ks -= K;
  float v = 0.f;
  if (nn < N){
    v = Wa[(size_t)(ks+rowoff)*N + nn];
    if (Wb) v -= Wb[(size_t)(ks+rowoff)*N + nn];
  }
  Wt[idx] = f2b(v);
}

// ---------------------------------------------------------------------------
// 64-row 32x32x16 MFMA phase, FULL-PHASE WEIGHT PRELOAD (8 steps, K=128).
// NAMED registers r0..r7 + hand-unrolled steps (rule #20: a pragma-unrolled
// r[ks] array is runtime-indexed at SROA time and goes to scratch — R13).
// Only the first barrier pays vmem-drain latency; the other 15 are free.
// ---------------------------------------------------------------------------
template<int KSTRIDE, int NCOLTOT>
__device__ __forceinline__ void mm32(
    const short* __restrict__ Wt, int kbase,
    short (*As)[258], short (*Bs)[28],
    int t, int lane, int w, f32x16* acc)
{
  constexpr int NT = (NCOLTOT>=64)? NCOLTOT/64 : 1;
  const int lane31 = lane & 31, kh = lane >> 5;
  const int arow = (w>>1)*32 + lane31;
  const int colbase = (NCOLTOT>=64)? (w&1)*(NCOLTOT/2) : 0;
  const bool act = (t < NCOLTOT*2);
  const int col = t >> 1, half = t & 1;
  const short* wp = Wt + (size_t)col*KSTRIDE + half*8;
  float4 r0,r1,r2,r3,r4,r5,r6,r7;
  if (act){
    r0 = *(const float4*)(wp +   0);
    r1 = *(const float4*)(wp +  16);
    r2 = *(const float4*)(wp +  32);
    r3 = *(const float4*)(wp +  48);
    r4 = *(const float4*)(wp +  64);
    r5 = *(const float4*)(wp +  80);
    r6 = *(const float4*)(wp +  96);
    r7 = *(const float4*)(wp + 112);
  }
#define MM32_STEP(KS, RV)                                                     \
  {                                                                           \
    if (act) *(float4*)&Bs[col][half*8] = RV;                                 \
    __syncthreads();                                                          \
    const bf16x8 a = *(const bf16x8*)&As[arow][kbase + (KS)*16 + kh*8];       \
    _Pragma("unroll")                                                         \
    for (int ct=0; ct<NT; ++ct){                                              \
      const bf16x8 b = *(const bf16x8*)&Bs[colbase + ct*32 + lane31][kh*8];   \
      acc[ct] = __builtin_amdgcn_mfma_f32_32x32x16_bf16(a, b, acc[ct],0,0,0); \
    }                                                                         \
    __syncthreads();                                                          \
  }
  MM32_STEP(0,r0) MM32_STEP(1,r1) MM32_STEP(2,r2) MM32_STEP(3,r3)
  MM32_STEP(4,r4) MM32_STEP(5,r5) MM32_STEP(6,r6) MM32_STEP(7,r7)
#undef MM32_STEP
}

// C-row within 32-row tile for accumulator register `reg` (m74/m101 layout)
__device__ __forceinline__ int rowof(int reg, int kh){
  return (reg & 3) + ((reg >> 2) << 3) + (kh << 2);
}

// ---------------------------------------------------------------------------
// k_pa: per-node precompute (bf16 MFMA, 64-row tiles, coalesced stores):
//   PAs[n] = [P1 | A1] = [niB@Wtop(nred) | nf@(W1top-W1bot)]  (bf16)
//   PAd[n] = [P2 | A2] = [niB@Wbot(nred) | nf@W1bot]          (bf16)
// ---------------------------------------------------------------------------
__global__ __launch_bounds__(256, 2) void k_pa(
  const float* __restrict__ niB, const float* __restrict__ nf,
  const short* __restrict__ wt_p1, const short* __restrict__ wt_p2,
  const short* __restrict__ wt_a1, const short* __restrict__ wt_a2,
  short* __restrict__ PAs, short* __restrict__ PAd, int n)
{
  __shared__ short As[64][258];    // 33024 B
  __shared__ short Out[64][136];   // 17408 B
  __shared__ short Bs[128][28];    //  7168 B  -> 57600 total
  const int t = threadIdx.x, lane = t & 63, w = t >> 6;
  const int lane31 = lane & 31, kh = lane >> 5;
  const int n0 = blockIdx.x * 64;
  const int srow = t >> 2, q = t & 3;
  const int grow = n0 + srow;

#define STAGE_SRC(SRC)                                                       \
  {                                                                          \
    short* dst = &As[srow][q*32];                                            \
    if (grow < n){                                                           \
      const float* src = (SRC) + (size_t)grow*128 + q*32;                    \
      _Pragma("unroll")                                                      \
      for (int p=0;p<4;p++){                                                 \
        float4 u=ld4(src+p*8), v=ld4(src+p*8+4);                             \
        bf16x8 o;                                                            \
        o[0]=f2b(u.x);o[1]=f2b(u.y);o[2]=f2b(u.z);o[3]=f2b(u.w);             \
        o[4]=f2b(v.x);o[5]=f2b(v.y);o[6]=f2b(v.z);o[7]=f2b(v.w);             \
        *(bf16x8*)(dst+p*8)=o;                                               \
      }                                                                      \
    } else {                                                                 \
      _Pragma("unroll")                                                      \
      for (int p=0;p<4;p++) *(bf16x8*)(dst+p*8) = (bf16x8)0;                 \
    }                                                                        \
  }

#define OUT_AND_STORE(DST, CB)                                               \
  {                                                                          \
    const int colbase = (w&1)*64;                                            \
    _Pragma("unroll")                                                        \
    for (int ct=0;ct<2;ct++){                                                \
      _Pragma("unroll")                                                      \
      for (int reg=0;reg<16;reg++)                                           \
        Out[(w>>1)*32 + rowof(reg,kh)][colbase + ct*32 + lane31] =           \
            f2b(acc[ct][reg]);                                               \
    }                                                                        \
    __syncthreads();                                                         \
    if (grow < n){                                                           \
      const float* srcp = (const float*)&Out[srow][q*32];                    \
      float* dstp = (float*)((DST) + (size_t)grow*256 + (CB) + q*32);        \
      _Pragma("unroll")                                                      \
      for (int p=0;p<4;p++) st4(dstp + p*4, ld4(srcp + p*4));                \
    }                                                                        \
    __syncthreads();                                                         \
  }

  f32x16 acc[2];
  // phase A: niB -> P1, P2
  STAGE_SRC(niB);
  acc[0]=(f32x16)(0.f); acc[1]=(f32x16)(0.f);
  mm32<128,128>(wt_p1, 0, As, Bs, t, lane, w, acc);
  OUT_AND_STORE(PAs, 0);
  acc[0]=(f32x16)(0.f); acc[1]=(f32x16)(0.f);
  mm32<128,128>(wt_p2, 0, As, Bs, t, lane, w, acc);
  OUT_AND_STORE(PAd, 0);
  // phase B: nf -> A1, A2
  STAGE_SRC(nf);
  acc[0]=(f32x16)(0.f); acc[1]=(f32x16)(0.f);
  mm32<128,128>(wt_a1, 0, As, Bs, t, lane, w, acc);
  OUT_AND_STORE(PAs, 128);
  acc[0]=(f32x16)(0.f); acc[1]=(f32x16)(0.f);
  mm32<128,128>(wt_a2, 0, As, Bs, t, lane, w, acc);
  OUT_AND_STORE(PAd, 128);
#undef STAGE_SRC
#undef OUT_AND_STORE
}

// ---------------------------------------------------------------------------
// Fused edge kernel (bf16 MFMA 32x32x16, 256 thr, 64 edges/block, 40KB LDS):
//   ef1 = relu(A1[s]+A2[d]+b1)*sigm(P1[s]+P2[d]+bg)  [elementwise staging]
//   emlp2 + elin1(BN,leaky) + elin2 -> elog
// ---------------------------------------------------------------------------
__global__ __launch_bounds__(256, 4) void k_edge(
  const short* __restrict__ PAs, const short* __restrict__ PAd,
  const int* __restrict__ eidx,
  const float* __restrict__ nredb, const float* __restrict__ e1b,
  const short* __restrict__ wt_e2, const float* __restrict__ e2b,
  const short* __restrict__ wt_l1, const float* __restrict__ ebng, const float* __restrict__ ebnb,
  const short* __restrict__ wt_l2,
  float* __restrict__ elog)
{
  __shared__ short As[64][258];    // 33024 B
  __shared__ short Bs[128][28];    //  7168 B -> 40192 total (4 blocks/CU)
  const int t = threadIdx.x, lane = t & 63, w = t >> 6;
  const int lane31 = lane & 31, kh = lane >> 5;
  const int row0 = blockIdx.x * 64;

  // ---- staging: gather + elementwise gate/emlp1 -> ef1 in As cols 0..127
  {
    const int srow = t >> 2, q = t & 3;
    const int e = row0 + srow;
    const int s = eidx[2*e], d = eidx[2*e+1];
    const short* ps = PAs + (size_t)s*256;
    const short* pd = PAd + (size_t)d*256;
    #pragma unroll
    for (int c0=0;c0<32;c0+=8){
      const int c = q*32 + c0;
      const bf16x8 p1 = *(const bf16x8*)(ps + c);
      const bf16x8 p2 = *(const bf16x8*)(pd + c);
      const bf16x8 a1 = *(const bf16x8*)(ps + 128 + c);
      const bf16x8 a2 = *(const bf16x8*)(pd + 128 + c);
      const float4 bg0=ld4(nredb+c), bg1=ld4(nredb+c+4);
      const float4 be0=ld4(e1b+c),   be1=ld4(e1b+c+4);
      const float bg[8]={bg0.x,bg0.y,bg0.z,bg0.w,bg1.x,bg1.y,bg1.z,bg1.w};
      const float be[8]={be0.x,be0.y,be0.z,be0.w,be1.x,be1.y,be1.z,be1.w};
      bf16x8 o;
      #pragma unroll
      for (int j=0;j<8;j++){
        const float g = sigm(b2f(p1[j]) + b2f(p2[j]) + bg[j]);
        const float v = fmaxf(b2f(a1[j]) + b2f(a2[j]) + be[j], 0.f) * g;
        o[j] = f2b(v);
      }
      *(bf16x8*)&As[srow][c] = o;
    }
  }

  f32x16 acc[2];
  // ---- emlp2 half 0: ef2 cols 0..127 -> As cols 128..255
  acc[0]=(f32x16)(0.f); acc[1]=(f32x16)(0.f);
  mm32<128,128>(wt_e2, 0, As, Bs, t, lane, w, acc);
  #pragma unroll
  for (int ct=0;ct<2;ct++){
    const int col = (w&1)*64 + ct*32 + lane31;
    const float bb = e2b[col];
    #pragma unroll
    for (int reg=0;reg<16;reg++)
      As[(w>>1)*32 + rowof(reg,kh)][128+col] = f2b(fmaxf(acc[ct][reg] + bb, 0.f));
  }
  // ---- emlp2 half 1: ef2 cols 128..255 -> As cols 0..127 (over ef1)
  acc[0]=(f32x16)(0.f); acc[1]=(f32x16)(0.f);
  mm32<128,128>(wt_e2 + (size_t)128*128, 0, As, Bs, t, lane, w, acc);
  #pragma unroll
  for (int ct=0;ct<2;ct++){
    const int col = (w&1)*64 + ct*32 + lane31;
    const float bb = e2b[128+col];
    #pragma unroll
    for (int reg=0;reg<16;reg++)
      As[(w>>1)*32 + rowof(reg,kh)][col] = f2b(fmaxf(acc[ct][reg] + bb, 0.f));
  }

  // ---- elin1 (256 -> 128) in two K=128 halves (acc carries across calls);
  //      weights k-rotated by 128 at prep time to match As ping-pong layout
  acc[0]=(f32x16)(0.f); acc[1]=(f32x16)(0.f);
  mm32<256,128>(wt_l1,       0,   As, Bs, t, lane, w, acc);
  mm32<256,128>(wt_l1 + 128, 128, As, Bs, t, lane, w, acc);
  {
    const float r_ = rsqrtf(1.f + 1e-5f);
    #pragma unroll
    for (int ct=0;ct<2;ct++){
      const int col = (w&1)*64 + ct*32 + lane31;
      const float sc = ebng[col]*r_, sh = ebnb[col];
      #pragma unroll
      for (int reg=0;reg<16;reg++){
        const float x = fmaf(acc[ct][reg], sc, sh);
        As[(w>>1)*32 + rowof(reg,kh)][col] = f2b((x>0.f)? x : 0.2f*x);
      }
    }
  }

  // ---- elin2 (128 -> 27, padded 32); all waves compute same 32 cols
  f32x16 acc5 = (f32x16)(0.f);
  mm32<128,32>(wt_l2, 0, As, Bs, t, lane, w, &acc5);

  float* Lb = (float*)&As[0][0];   // [64][28] fp32
  if ((w&1)==0 && lane31 < 27){
    #pragma unroll
    for (int reg=0;reg<16;reg++)
      Lb[((w>>1)*32 + rowof(reg,kh))*28 + lane31] = acc5[reg];
  }
  __syncthreads();
  for (int i=t; i<64*27; i+=256){
    int rr = i/27, cc = i - rr*27;
    elog[(size_t)(row0+rr)*27 + cc] = Lb[rr*28 + cc];
  }
}

// ---------------------------- tail kernels --------------------------------
__global__ __launch_bounds__(256) void k_softmax_row(float* __restrict__ x, int M){
  const int wave = threadIdx.x>>6, lane = threadIdx.x&63;
  const int r = blockIdx.x*4 + wave; if (r>=M) return;
  float* p = x + (size_t)r*160;
  float v0 = p[lane], v1 = p[64+lane];
  float v2 = (lane<32)? p[128+lane] : -3.4e38f;
  float m = fmaxf(fmaxf(v0,v1),v2);
  for (int o=32;o;o>>=1) m = fmaxf(m, __shfl_xor(m,o));
  float e0=expf(v0-m), e1=expf(v1-m), e2=(lane<32)?expf(v2-m):0.f;
  float s=e0+e1+e2;
  for (int o=32;o;o>>=1) s += __shfl_xor(s,o);
  float inv = 1.f/s;
  p[lane]=e0*inv; p[64+lane]=e1*inv; if(lane<32)p[128+lane]=e2*inv;
}
__global__ void k_colmax(const float* __restrict__ x, uint32* __restrict__ cmax_u, int E){
  __shared__ float red[8][32];
  const int t=threadIdx.x, col=t&31, seg=t>>5;
  float m = -3.4e38f;
  if (col < 27)
    for (int r = blockIdx.x*8 + seg; r < E; r += gridDim.x*8)
      m = fmaxf(m, x[(size_t)r*27+col]);
  red[seg][col]=m; __syncthreads();
  if (t<32){
    float mm=red[0][t];
    #pragma unroll
    for (int s2=1;s2<8;s2++) mm=fmaxf(mm,red[s2][t]);
    if (t<27){
      uint32 u=__float_as_uint(mm);
      u = (u&0x80000000u)? ~u : (u|0x80000000u);
      atomicMax(&cmax_u[t], u);
    }
  }
}
__global__ void k_colfix(const uint32* __restrict__ cmax_u, float* __restrict__ cmaxf){
  int t=threadIdx.x; if (t>=27) return;
  uint32 u=cmax_u[t];
  cmaxf[t] = (u&0x80000000u)? __uint_as_float(u&0x7FFFFFFFu) : __uint_as_float(~u);
}
__global__ void k_colsum(const float* __restrict__ x, const float* __restrict__ cmaxf,
                         float* __restrict__ csum, int E){
  __shared__ float red[8][32];
  const int t=threadIdx.x, col=t&31, seg=t>>5;
  float s = 0.f;
  if (col < 27){
    const float cm = cmaxf[col];
    for (int r = blockIdx.x*8 + seg; r < E; r += gridDim.x*8)
      s += expf(x[(size_t)r*27+col] - cm);
  }
  red[seg][col]=s; __syncthreads();
  if (t<32){
    float ss=red[0][t];
    #pragma unroll
    for (int s2=1;s2<8;s2++) ss+=red[s2][t];
    if (t<27) atomicAdd(&csum[t], ss);
  }
}
__global__ void k_colnorm(float* __restrict__ x, const float* __restrict__ cmaxf,
                          const float* __restrict__ csum, int E){
  int idx=blockIdx.x*256+threadIdx.x;
  if (idx >= E*27) return;
  int c = idx - (idx/27)*27;
  x[idx] = expf(x[idx]-cmaxf[c]) / csum[c];
}

// ---------------------------------------------------------------------------
extern "C" void kernel_launch(void* const* d_in, const int* in_sizes, int n_in,
                              void* d_out, int out_size, void* d_ws, size_t ws_size,
                              hipStream_t stream)
{
  const float* nf     = (const float*)d_in[0];
  const int*   eidx   = (const int*)  d_in[1];
  const float* gcn1W  = (const float*)d_in[2];
  const float* gcn1b  = (const float*)d_in[3];
  const float* gcn2W  = (const float*)d_in[4];
  const float* gcn2b  = (const float*)d_in[5];
  const float* eattnW = (const float*)d_in[6];
  const float* eattnb = (const float*)d_in[7];
  const float* nattnW = (const float*)d_in[8];
  const float* nattnb = (const float*)d_in[9];
  const float* nredW  = (const float*)d_in[10];
  const float* nredb  = (const float*)d_in[11];
  const float* emlp1W = (const float*)d_in[12];
  const float* emlp1b = (const float*)d_in[13];
  const float* emlp2W = (const float*)d_in[14];
  const float* emlp2b = (const float*)d_in[15];
  const float* nlin1W = (const float*)d_in[16];
  const float* nbng   = (const float*)d_in[17];
  const float* nbnb   = (const float*)d_in[18];
  const float* nlin2W = (const float*)d_in[19];
  const float* elin1W = (const float*)d_in[20];
  const float* ebng   = (const float*)d_in[21];
  const float* ebnb   = (const float*)d_in[22];
  const float* elin2W = (const float*)d_in[23];
  (void)in_sizes; (void)n_in; (void)out_size; (void)ws_size;

  const int N = NN, E = EE;
  float* out  = (float*)d_out;
  float* nlog = out;                       // N*160
  float* elog = out + (size_t)N*160;       // E*27

  // ---- workspace plan (~237 MB, PAs/PAd overlay TUL+h1) ----
  float* ws   = (float*)d_ws;
  float* h2   = ws;                        // N*128
  float* lin2 = ws + (size_t)N*128;        // N*128 ; Q/S early, niB/nx later
  float* Q    = lin2;                      // N*64
  float* S    = lin2 + (size_t)N*64;       // N*64
  float* niB  = lin2;
  float* nx   = lin2;
  float* TUL  = ws + (size_t)N*256;        // N*192  [T|U|lin1]  (dead before k_pa)
  float* h1   = ws + (size_t)N*448;        // N*64              (dead before k_pa)
  short* PAs  = (short*)TUL;               // N*256 bf16
  short* PAd  = PAs + (size_t)N*256;       // N*256 bf16
  float* aei  = ws + (size_t)N*512;        // N*64
  float* dis  = ws + (size_t)N*576;        // N
  float* smalls = ws + (size_t)N*577;      // 96
  float* Wcat = smalls + 128;              // 128*192
  int*   ip   = (int*)(Wcat + 24576);
  int* cntS = ip;                          // N
  int* cntD = ip + N;                      // N
  int* offS = ip + 2*N;                    // N+64
  int* offD = ip + 3*N + 64;               // N+64
  int* curS = ip + 4*N + 128;              // N
  int* curD = ip + 5*N + 128;              // N
  int* csrS = ip + 6*N + 128;              // E
  int* csrD = ip + 6*N + 128 + E;          // E
  int* bsum = ip + 6*N + 128 + 2*E;        // 256
  short* wtb  = (short*)(bsum + 256);
  short* wt_p1 = wtb;                      // 128*128
  short* wt_p2 = wtb + 16384;              // 128*128
  short* wt_a1 = wtb + 32768;              // 128*128
  short* wt_a2 = wtb + 49152;              // 128*128
  short* wt_e2 = wtb + 65536;              // 256*128
  short* wt_l1 = wtb + 98304;              // 128*256
  short* wt_l2 = wtb + 131072;             // 32*128

  const int NB1024 = (N + 1023)/1024;      // 98

  // 0. weight prep
  k_twtg<<<64, 256,0,stream>>>(nredW,  nullptr, wt_p1, 128,128,128, 0,   0);
  k_twtg<<<64, 256,0,stream>>>(nredW,  nullptr, wt_p2, 128,128,128, 128, 0);
  k_twtg<<<64, 256,0,stream>>>(emlp1W, emlp1W+(size_t)128*128, wt_a1, 128,128,128, 0, 0);
  k_twtg<<<64, 256,0,stream>>>(emlp1W, nullptr, wt_a2, 128,128,128, 128, 0);
  k_twtg<<<128,256,0,stream>>>(emlp2W, nullptr, wt_e2, 128,256,256, 0,   0);
  k_twtg<<<128,256,0,stream>>>(elin1W, nullptr, wt_l1, 256,128,128, 0, 128);
  k_twtg<<<16, 256,0,stream>>>(elin2W, nullptr, wt_l2, 128,27, 32,  0,   0);
  k_wprep<<<96,256,0,stream>>>(eattnW, gcn1W, Wcat);

  // 1. CSR build (both directions)
  (void)hipMemsetAsync(cntS, 0, 2*(size_t)N*sizeof(int), stream);
  k_hist<<<(E+255)/256,256,0,stream>>>(eidx, cntS, cntD, E);
  k_scan_sum<<<NB1024,256,0,stream>>>(cntS, bsum, N);
  k_scan_top<<<1,256,0,stream>>>(bsum, NB1024);
  k_scan_out<<<NB1024,256,0,stream>>>(cntS, bsum, offS, N);
  k_scan_sum<<<NB1024,256,0,stream>>>(cntD, bsum, N);
  k_scan_top<<<1,256,0,stream>>>(bsum, NB1024);
  k_scan_out<<<NB1024,256,0,stream>>>(cntD, bsum, offD, N);
  k_setend<<<1,64,0,stream>>>(offS, offD, N, E);
  k_copyoff<<<(N+255)/256,256,0,stream>>>(offS, curS, N);
  k_copyoff<<<(N+255)/256,256,0,stream>>>(offD, curD, N);
  k_fill<<<(E+255)/256,256,0,stream>>>(eidx, curS, curD, csrS, csrD, E);
  k_dis<<<(N+255)/256,256,0,stream>>>(cntD, dis, N);

  // 2. TUL = nf @ [Wbot|Wd|gcn1W]
  gemm_k<128,192,EM_STORE><<<(N+63)/64,256,0,stream>>>(nf, Wcat, nullptr, nullptr, TUL, N);

  // 3. eattn segment means via gathers
  k_gather<64><<<(N+15)/16,256,0,stream>>>(TUL, 192, 0,  offS, csrS, Q, N);
  k_gather<64><<<(N+15)/16,256,0,stream>>>(TUL, 192, 64, offD, csrD, S, N);
  k_aei3<<<(N*16+255)/256,256,0,stream>>>(TUL, Q, S, cntS, cntD, eattnb, aei, N);

  // 4. GCN conv 1
  k_gcnagg<64,true><<<(N+15)/16,256,0,stream>>>(TUL, 192, 128, offD, csrD, dis, aei, gcn1b, h1, N);

  // 5. GCN conv 2
  gemm_k<64,128,EM_STORE><<<(N+63)/64,256,0,stream>>>(h1, gcn2W, nullptr, nullptr, lin2, N);
  k_gcnagg<128,false><<<(N+7)/8,256,0,stream>>>(lin2, 128, 0, offD, csrD, dis, nullptr, gcn2b, h2, N);

  // 6. node attention
  gemm_k<128,128,EM_BRELU><<<(N+63)/64,256,0,stream>>>(h2, nattnW, nattnb, nullptr, niB, N);

  // 7. per-node gate/emlp1 halves (overwrites TUL/h1 region)
  k_pa<<<(N+63)/64,256,0,stream>>>(niB, nf, wt_p1, wt_p2, wt_a1, wt_a2, PAs, PAd, N);

  // 8. fused edge chain (bf16 MFMA 32x32x16, named-reg phase preload)
  k_edge<<<E/64,256,0,stream>>>(
      PAs, PAd, eidx,
      nredb, emlp1b, wt_e2, emlp2b,
      wt_l1, ebng, ebnb, wt_l2, elog);

  // 9. node head
  gemm_k<128,64,EM_BNLK><<<(N+63)/64,256,0,stream>>>(h2, nlin1W, nbnb, nbng, nx, N);
  gemm_k<64,160,EM_STORE><<<(N+63)/64,256,0,stream>>>(nx, nlin2W, nullptr, nullptr, nlog, N);
  k_softmax_row<<<(N+3)/4,256,0,stream>>>(nlog, N);

  // 10. column softmax over E (in place in d_out)
  (void)hipMemsetAsync(smalls, 0, 96*sizeof(float), stream);
  k_colmax<<<1024,256,0,stream>>>(elog, (uint32*)smalls, E);
  k_colfix<<<1,32,0,stream>>>((const uint32*)smalls, smalls+64);
  k_colsum<<<1024,256,0,stream>>>(elog, smalls+64, smalls+32, E);
  k_colnorm<<<(E*27+255)/256,256,0,stream>>>(elog, smalls+64, smalls+32, E);
}

// Round 15
// 1021.830 us; speedup vs baseline: 1.1351x; 1.0291x over previous
//
#include <hip/hip_runtime.h>

#define NN 100000
#define EE 320000

typedef unsigned int uint32;
typedef __attribute__((ext_vector_type(8))) short bf16x8;
typedef __attribute__((ext_vector_type(4))) float f32x4;
typedef __attribute__((ext_vector_type(16))) float f32x16;

__device__ __forceinline__ float4 ld4(const float* p){ return *(const float4*)p; }
__device__ __forceinline__ void st4(float* p, const float4 v){ *(float4*)p = v; }
__device__ __forceinline__ float sigm(float x){ return 1.f/(1.f + expf(-x)); }
__device__ __forceinline__ short f2b(float f){
  union { float f; uint32 u; } v; v.f = f;
  uint32 r = (v.u + 0x7FFFu + ((v.u>>16)&1u)) >> 16;   // RNE
  return (short)r;
}
__device__ __forceinline__ float b2f(short s){
  union { uint32 u; float f; } v; v.u = ((uint32)(unsigned short)s) << 16; return v.f;
}

constexpr int EM_STORE=0, EM_BRELU=1, EM_BNLK=2;

// ---------------------------------------------------------------------------
// Generic fp32 tiled GEMM (node path): 64 rows/block, BK=16, 256 threads.
// ---------------------------------------------------------------------------
template<int K,int NOUT,int EM>
__global__ __launch_bounds__(256) void gemm_k(
    const float* __restrict__ A,
    const float* __restrict__ W, const float* __restrict__ bias,
    const float* __restrict__ bng,
    float* __restrict__ C, int M)
{
  constexpr int CN = NOUT/16;
  __shared__ float As[16][68];
  __shared__ float Ws[16][NOUT];
  const int t  = threadIdx.x;
  const int tx = t & 15, ty = t >> 4;
  const int row0 = blockIdx.x * 64;

  float acc[4][CN];
  #pragma unroll
  for (int i=0;i<4;i++)
    #pragma unroll
    for (int j=0;j<CN;j++) acc[i][j]=0.f;

  const int r_st  = t >> 2;
  const int kq_st = (t & 3) * 4;

  for (int k0=0;k0<K;k0+=16) {
    {
      float4 v = make_float4(0.f,0.f,0.f,0.f);
      const int gr = row0 + r_st;
      if (gr < M) v = ld4(A + (size_t)gr*K + k0 + kq_st);
      As[kq_st+0][r_st]=v.x; As[kq_st+1][r_st]=v.y;
      As[kq_st+2][r_st]=v.z; As[kq_st+3][r_st]=v.w;
    }
    {
      constexpr int C4 = NOUT/4;
      for (int i=t;i<16*C4;i+=256){ int kk=i/C4, c4=(i%C4)*4;
        st4(&Ws[kk][c4], ld4(W + (size_t)(k0+kk)*NOUT + c4)); }
    }
    __syncthreads();
    #pragma unroll
    for (int kk=0;kk<16;kk++){
      float a0,a1,a2,a3;
      { const float4 av = *(const float4*)&As[kk][ty*4]; a0=av.x;a1=av.y;a2=av.z;a3=av.w; }
      float b[CN];
      if constexpr ((CN & 3) == 0) {
        #pragma unroll
        for (int j4=0;j4<CN;j4+=4){
          const float4 bv = *(const float4*)&Ws[kk][tx*CN+j4];
          b[j4]=bv.x;b[j4+1]=bv.y;b[j4+2]=bv.z;b[j4+3]=bv.w; }
      } else {
        #pragma unroll
        for (int j=0;j<CN;j++) b[j]=Ws[kk][tx*CN+j];
      }
      #pragma unroll
      for (int j=0;j<CN;j++){
        acc[0][j]=fmaf(a0,b[j],acc[0][j]);
        acc[1][j]=fmaf(a1,b[j],acc[1][j]);
        acc[2][j]=fmaf(a2,b[j],acc[2][j]);
        acc[3][j]=fmaf(a3,b[j],acc[3][j]);
      }
    }
    __syncthreads();
  }

  float sc[CN], sh[CN];
  if constexpr (EM==EM_BNLK) {
    const float r_ = rsqrtf(1.f + 1e-5f);
    #pragma unroll
    for (int j=0;j<CN;j++){ int c=tx*CN+j; sc[j]=bng[c]*r_; sh[j]=bias[c]; }
  }
  #pragma unroll
  for (int i=0;i<4;i++){
    const int r  = row0 + ty*4+i;
    if (r >= M) continue;
    #pragma unroll
    for (int j=0;j<CN;j++){
      const int c = tx*CN+j;
      float v = acc[i][j];
      if constexpr (EM==EM_BRELU) v = fmaxf(v + bias[c], 0.f);
      else if constexpr (EM==EM_BNLK){ float x = fmaf(v, sc[j], sh[j]); v = (x>0.f)? x : 0.2f*x; }
      C[(size_t)r*NOUT + c] = v;
    }
  }
}

// ---------------------------------------------------------------------------
// CSR build: histogram -> scan -> fill
// ---------------------------------------------------------------------------
__global__ void k_hist(const int* __restrict__ eidx, int* cntS, int* cntD, int E){
  int e = blockIdx.x*256+threadIdx.x; if (e>=E) return;
  atomicAdd(&cntS[eidx[2*e]], 1);
  atomicAdd(&cntD[eidx[2*e+1]], 1);
}
__global__ void k_scan_sum(const int* __restrict__ cnt, int* bsum, int n){
  __shared__ int red[256];
  const int b=blockIdx.x, t=threadIdx.x;
  int s=0;
  for (int i=b*1024+t; i<n && i<(b+1)*1024; i+=256) s += cnt[i];
  red[t]=s; __syncthreads();
  for (int o=128;o;o>>=1){ if(t<o) red[t]+=red[t+o]; __syncthreads(); }
  if (t==0) bsum[b]=red[0];
}
__global__ void k_scan_top(int* bsum, int nb){
  __shared__ int sh[256];
  const int t=threadIdx.x;
  int v=(t<nb)?bsum[t]:0;
  sh[t]=v; __syncthreads();
  for (int o=1;o<256;o<<=1){
    int u=0; if(t>=o) u=sh[t-o];
    __syncthreads();
    sh[t]+=u;
    __syncthreads();
  }
  if (t<nb) bsum[t]=sh[t]-v;
}
__global__ void k_scan_out(const int* __restrict__ cnt, const int* __restrict__ bofs,
                           int* __restrict__ off, int n){
  __shared__ int sh[256];
  const int b=blockIdx.x, t=threadIdx.x;
  const int base=b*1024+t*4;
  int c0=0,c1=0,c2=0,c3=0;
  if(base+0<n)c0=cnt[base+0];
  if(base+1<n)c1=cnt[base+1];
  if(base+2<n)c2=cnt[base+2];
  if(base+3<n)c3=cnt[base+3];
  int s=c0+c1+c2+c3;
  sh[t]=s; __syncthreads();
  int v=s;
  for (int o=1;o<256;o<<=1){
    int u=0; if(t>=o) u=sh[t-o];
    __syncthreads();
    sh[t]+=u;
    __syncthreads();
  }
  const int tofs = sh[t]-v + bofs[b];
  if(base+0<n) off[base+0]=tofs;
  if(base+1<n) off[base+1]=tofs+c0;
  if(base+2<n) off[base+2]=tofs+c0+c1;
  if(base+3<n) off[base+3]=tofs+c0+c1+c2;
}
__global__ void k_copyoff(const int* __restrict__ off, int* __restrict__ cur, int n){
  int i=blockIdx.x*256+threadIdx.x;
  if (i<n) cur[i]=off[i];
}
__global__ void k_setend(int* offS, int* offD, int n, int E){
  if (threadIdx.x==0 && blockIdx.x==0){ offS[n]=E; offD[n]=E; }
}
__global__ void k_fill(const int* __restrict__ eidx, int* curS, int* curD,
                       int* __restrict__ csrS, int* __restrict__ csrD, int E){
  int e=blockIdx.x*256+threadIdx.x; if (e>=E) return;
  const int s=eidx[2*e], d=eidx[2*e+1];
  csrS[atomicAdd(&curS[s],1)] = d;
  csrD[atomicAdd(&curD[d],1)] = s;
}
__global__ void k_dis(const int* __restrict__ cntD, float* __restrict__ dis, int n){
  int i=blockIdx.x*256+threadIdx.x; if(i>=n)return;
  dis[i]=rsqrtf((float)cntD[i]+1.f);
}

// ---------------------------------------------------------------------------
// Wcat = [Wbot | Wd | gcn1W]  (128 x 192 fp32)
// ---------------------------------------------------------------------------
__global__ void k_wprep(const float* __restrict__ eattnW, const float* __restrict__ gcn1W,
                        float* __restrict__ Wcat){
  int idx=blockIdx.x*256+threadIdx.x; if (idx>=128*192) return;
  int k=idx/192, c=idx-k*192;
  float v;
  if (c<64)       v = eattnW[(size_t)(128+k)*64 + c];
  else if (c<128) v = eattnW[(size_t)k*64 + (c-64)] - eattnW[(size_t)(128+k)*64 + (c-64)];
  else            v = gcn1W[(size_t)k*64 + (c-128)];
  Wcat[idx]=v;
}

// ---------------------------------------------------------------------------
// CSR gather-sum
// ---------------------------------------------------------------------------
template<int NC>
__global__ void k_gather(const float* __restrict__ src, int stride, int colbase,
                         const int* __restrict__ off, const int* __restrict__ csr,
                         float* __restrict__ out, int n){
  constexpr int TPN = NC/4;
  const int t=threadIdx.x;
  const int node = blockIdx.x*(256/TPN) + t/TPN; if (node>=n) return;
  const int cq = (t%TPN)*4;
  const int j1=off[node+1];
  float4 acc = make_float4(0.f,0.f,0.f,0.f);
  for (int j=off[node]; j<j1; ++j){
    const float4 v = ld4(src + (size_t)csr[j]*stride + colbase + cq);
    acc.x+=v.x; acc.y+=v.y; acc.z+=v.z; acc.w+=v.w;
  }
  st4(out + (size_t)node*NC + cq, acc);
}

// aei = sigmoid(row*col)
__global__ void k_aei3(const float* __restrict__ TUL, const float* __restrict__ Q,
                       const float* __restrict__ S, const int* __restrict__ cntS,
                       const int* __restrict__ cntD, const float* __restrict__ bias,
                       float* __restrict__ aei, int n){
  int idx=blockIdx.x*256+threadIdx.x; if (idx>=n*16) return;
  const int i=idx>>4, cq=(idx&15)*4;
  const float cS=(float)cntS[i], cD=(float)cntD[i];
  const float iS=1.f/fmaxf(cS,1.f), iD=1.f/fmaxf(cD,1.f);
  const float* tul = TUL + (size_t)i*192;
  const float4 T4=ld4(tul+cq), U4=ld4(tul+64+cq);
  const float4 Q4=ld4(Q+(size_t)i*64+cq), S4=ld4(S+(size_t)i*64+cq), b4=ld4(bias+cq);
  float4 o;
  o.x=sigm(((cS*(U4.x+b4.x)+Q4.x)*iS) * ((cD*(T4.x+b4.x)+S4.x)*iD));
  o.y=sigm(((cS*(U4.y+b4.y)+Q4.y)*iS) * ((cD*(T4.y+b4.y)+S4.y)*iD));
  o.z=sigm(((cS*(U4.z+b4.z)+Q4.z)*iS) * ((cD*(T4.z+b4.z)+S4.z)*iD));
  o.w=sigm(((cS*(U4.w+b4.w)+Q4.w)*iS) * ((cD*(T4.w+b4.w)+S4.w)*iD));
  st4(aei + (size_t)i*64 + cq, o);
}

// GCN aggregate + combine
template<int NC, bool AEI>
__global__ void k_gcnagg(const float* __restrict__ lin, int stride, int colbase,
                         const int* __restrict__ off, const int* __restrict__ csr,
                         const float* __restrict__ dis, const float* __restrict__ aei,
                         const float* __restrict__ bias, float* __restrict__ h, int n){
  constexpr int TPN = NC/4;
  const int t=threadIdx.x;
  const int node = blockIdx.x*(256/TPN) + t/TPN; if (node>=n) return;
  const int cq = (t%TPN)*4;
  const int j1=off[node+1];
  float4 acc = make_float4(0.f,0.f,0.f,0.f);
  for (int j=off[node]; j<j1; ++j){
    const int s=csr[j];
    const float w=dis[s];
    const float4 v = ld4(lin + (size_t)s*stride + colbase + cq);
    acc.x=fmaf(v.x,w,acc.x); acc.y=fmaf(v.y,w,acc.y);
    acc.z=fmaf(v.z,w,acc.z); acc.w=fmaf(v.w,w,acc.w);
  }
  const float dn=dis[node], d2=dn*dn;
  const float4 own=ld4(lin + (size_t)node*stride + colbase + cq), b4=ld4(bias+cq);
  float4 o;
  o.x=fmaxf(fmaf(acc.x,dn,fmaf(own.x,d2,b4.x)),0.f);
  o.y=fmaxf(fmaf(acc.y,dn,fmaf(own.y,d2,b4.y)),0.f);
  o.z=fmaxf(fmaf(acc.z,dn,fmaf(own.z,d2,b4.z)),0.f);
  o.w=fmaxf(fmaf(acc.w,dn,fmaf(own.w,d2,b4.w)),0.f);
  if (AEI){ const float4 m=ld4(aei+(size_t)node*NC+cq); o.x*=m.x;o.y*=m.y;o.z*=m.z;o.w*=m.w; }
  st4(h + (size_t)node*NC + cq, o);
}

// ---------------------------------------------------------------------------
// Generic weight transpose + cast: Wt[NP][K] bf16,
// Wt[n][k] = (Wa - Wb?)[((k+krot)%K)+rowoff][n]
// ---------------------------------------------------------------------------
__global__ void k_twtg(const float* __restrict__ Wa, const float* __restrict__ Wb,
                       short* __restrict__ Wt, int K, int N, int NP, int rowoff, int krot){
  int idx = blockIdx.x*256 + threadIdx.x;
  if (idx >= NP*K) return;
  int nn = idx / K, k = idx - nn*K;
  int ks = k + krot; if (ks >= K) ks -= K;
  float v = 0.f;
  if (nn < N){
    v = Wa[(size_t)(ks+rowoff)*N + nn];
    if (Wb) v -= Wb[(size_t)(ks+rowoff)*N + nn];
  }
  Wt[idx] = f2b(v);
}

// ---------------------------------------------------------------------------
// 64-row 32x32x16 MFMA phase, PHASE-RESIDENT WEIGHT SLAB:
// the whole K=128 weight slab (NCOLTOT x 128 bf16) is staged into Bs ONCE,
// then all 8 k-steps run as pure LDS->MFMA with NO barriers and NO global
// loads in between (R10-R14: the per-step {load,drain,barrier} chain was the
// structural bottleneck; compiler kept sinking register preloads).
// Bs row stride 132 shorts (66 words, stride%32=2) -> ~2-way conflicts (free).
// 256 thr / 4 waves: wave w -> row-half (w>>1), col-half (w&1).
// A row = lane&31, k = (lane>>5)*8+j (same k-map as B -> perm-invariant).
// ---------------------------------------------------------------------------
template<int KSTRIDE, int NCOLTOT>
__device__ __forceinline__ void mm32(
    const short* __restrict__ Wt, int kbase,
    short (*As)[258], short (*Bs)[132],
    int t, int lane, int w, f32x16* acc)
{
  constexpr int NT = (NCOLTOT>=64)? NCOLTOT/64 : 1;
  const int lane31 = lane & 31, kh = lane >> 5;
  const int arow = (w>>1)*32 + lane31;
  const int colbase = (NCOLTOT>=64)? (w&1)*(NCOLTOT/2) : 0;
  // ---- stage whole slab: NCOLTOT cols x 128 k shorts = NCOLTOT*16 float4
  {
    constexpr int PER = (NCOLTOT*16)/256;   // 8 for 128 cols, 2 for 32 cols
    #pragma unroll
    for (int p=0;p<PER;p++){
      const int idx = t + p*256;
      const int col = idx >> 4, kq = idx & 15;   // 16 float4 per col
      *(float4*)&Bs[col][kq*8] = *(const float4*)(Wt + (size_t)col*KSTRIDE + kq*8);
    }
  }
  __syncthreads();
  // ---- 8 pure-LDS k-steps, no barriers
  #pragma unroll
  for (int ks=0; ks<8; ++ks){
    const bf16x8 a = *(const bf16x8*)&As[arow][kbase + ks*16 + kh*8];
    #pragma unroll
    for (int ct=0; ct<NT; ++ct){
      const bf16x8 b = *(const bf16x8*)&Bs[colbase + ct*32 + lane31][ks*16 + kh*8];
      acc[ct] = __builtin_amdgcn_mfma_f32_32x32x16_bf16(a, b, acc[ct], 0, 0, 0);
    }
  }
  __syncthreads();   // reads of As/Bs complete before caller overwrites
}

// C-row within 32-row tile for accumulator register `reg` (m74/m101 layout)
__device__ __forceinline__ int rowof(int reg, int kh){
  return (reg & 3) + ((reg >> 2) << 3) + (kh << 2);
}

// ---------------------------------------------------------------------------
// k_pa: per-node precompute (bf16 MFMA, 64-row tiles, coalesced stores):
//   PAs[n] = [P1 | A1] = [niB@Wtop(nred) | nf@(W1top-W1bot)]  (bf16)
//   PAd[n] = [P2 | A2] = [niB@Wbot(nred) | nf@W1bot]          (bf16)
// Out buffer ALIASES Bs (dead between phases) -> 65.3KB LDS, 2 blocks/CU.
// ---------------------------------------------------------------------------
__global__ __launch_bounds__(256, 2) void k_pa(
  const float* __restrict__ niB, const float* __restrict__ nf,
  const short* __restrict__ wt_p1, const short* __restrict__ wt_p2,
  const short* __restrict__ wt_a1, const short* __restrict__ wt_a2,
  short* __restrict__ PAs, short* __restrict__ PAd, int n)
{
  __shared__ short As[64][258];    // 33024 B
  __shared__ short Bs[128][132];   // 33792 B  -> 66816 total
  short* OutS = &Bs[0][0];         // Out[64][136] aliased into Bs (8704 shorts)
  const int t = threadIdx.x, lane = t & 63, w = t >> 6;
  const int lane31 = lane & 31, kh = lane >> 5;
  const int n0 = blockIdx.x * 64;
  const int srow = t >> 2, q = t & 3;
  const int grow = n0 + srow;

#define STAGE_SRC(SRC)                                                       \
  {                                                                          \
    short* dst = &As[srow][q*32];                                            \
    if (grow < n){                                                           \
      const float* src = (SRC) + (size_t)grow*128 + q*32;                    \
      _Pragma("unroll")                                                      \
      for (int p=0;p<4;p++){                                                 \
        float4 u=ld4(src+p*8), v=ld4(src+p*8+4);                             \
        bf16x8 o;                                                            \
        o[0]=f2b(u.x);o[1]=f2b(u.y);o[2]=f2b(u.z);o[3]=f2b(u.w);             \
        o[4]=f2b(v.x);o[5]=f2b(v.y);o[6]=f2b(v.z);o[7]=f2b(v.w);             \
        *(bf16x8*)(dst+p*8)=o;                                               \
      }                                                                      \
    } else {                                                                 \
      _Pragma("unroll")                                                      \
      for (int p=0;p<4;p++) *(bf16x8*)(dst+p*8) = (bf16x8)0;                 \
    }                                                                        \
  }

#define OUT_AND_STORE(DST, CB)                                               \
  {                                                                          \
    const int colbase = (w&1)*64;                                            \
    _Pragma("unroll")                                                        \
    for (int ct=0;ct<2;ct++){                                                \
      _Pragma("unroll")                                                      \
      for (int reg=0;reg<16;reg++)                                           \
        OutS[((w>>1)*32 + rowof(reg,kh))*136 + colbase + ct*32 + lane31] =   \
            f2b(acc[ct][reg]);                                               \
    }                                                                        \
    __syncthreads();                                                         \
    if (grow < n){                                                           \
      const float* srcp = (const float*)&OutS[srow*136 + q*32];              \
      float* dstp = (float*)((DST) + (size_t)grow*256 + (CB) + q*32);        \
      _Pragma("unroll")                                                      \
      for (int p=0;p<4;p++) st4(dstp + p*4, ld4(srcp + p*4));                \
    }                                                                        \
    __syncthreads();                                                         \
  }

  f32x16 acc[2];
  // phase A: niB -> P1, P2
  STAGE_SRC(niB);
  acc[0]=(f32x16)(0.f); acc[1]=(f32x16)(0.f);
  mm32<128,128>(wt_p1, 0, As, Bs, t, lane, w, acc);
  OUT_AND_STORE(PAs, 0);
  acc[0]=(f32x16)(0.f); acc[1]=(f32x16)(0.f);
  mm32<128,128>(wt_p2, 0, As, Bs, t, lane, w, acc);
  OUT_AND_STORE(PAd, 0);
  // phase B: nf -> A1, A2
  STAGE_SRC(nf);
  acc[0]=(f32x16)(0.f); acc[1]=(f32x16)(0.f);
  mm32<128,128>(wt_a1, 0, As, Bs, t, lane, w, acc);
  OUT_AND_STORE(PAs, 128);
  acc[0]=(f32x16)(0.f); acc[1]=(f32x16)(0.f);
  mm32<128,128>(wt_a2, 0, As, Bs, t, lane, w, acc);
  OUT_AND_STORE(PAd, 128);
#undef STAGE_SRC
#undef OUT_AND_STORE
}

// ---------------------------------------------------------------------------
// Fused edge kernel (bf16 MFMA 32x32x16, 256 thr, 64 edges/block, 65.3KB LDS):
//   ef1 = relu(A1[s]+A2[d]+b1)*sigm(P1[s]+P2[d]+bg)  [elementwise staging]
//   emlp2 + elin1(BN,leaky) + elin2 -> elog
// Phase-resident Bs slab -> ~12 barriers/block (was 80), no per-step drains.
// ---------------------------------------------------------------------------
__global__ __launch_bounds__(256, 2) void k_edge(
  const short* __restrict__ PAs, const short* __restrict__ PAd,
  const int* __restrict__ eidx,
  const float* __restrict__ nredb, const float* __restrict__ e1b,
  const short* __restrict__ wt_e2, const float* __restrict__ e2b,
  const short* __restrict__ wt_l1, const float* __restrict__ ebng, const float* __restrict__ ebnb,
  const short* __restrict__ wt_l2,
  float* __restrict__ elog)
{
  __shared__ short As[64][258];    // 33024 B
  __shared__ short Bs[128][132];   // 33792 B -> 66816 total (2 blocks/CU)
  const int t = threadIdx.x, lane = t & 63, w = t >> 6;
  const int lane31 = lane & 31, kh = lane >> 5;
  const int row0 = blockIdx.x * 64;

  // ---- staging: gather + elementwise gate/emlp1 -> ef1 in As cols 0..127
  {
    const int srow = t >> 2, q = t & 3;
    const int e = row0 + srow;
    const int s = eidx[2*e], d = eidx[2*e+1];
    const short* ps = PAs + (size_t)s*256;
    const short* pd = PAd + (size_t)d*256;
    #pragma unroll
    for (int c0=0;c0<32;c0+=8){
      const int c = q*32 + c0;
      const bf16x8 p1 = *(const bf16x8*)(ps + c);
      const bf16x8 p2 = *(const bf16x8*)(pd + c);
      const bf16x8 a1 = *(const bf16x8*)(ps + 128 + c);
      const bf16x8 a2 = *(const bf16x8*)(pd + 128 + c);
      const float4 bg0=ld4(nredb+c), bg1=ld4(nredb+c+4);
      const float4 be0=ld4(e1b+c),   be1=ld4(e1b+c+4);
      const float bg[8]={bg0.x,bg0.y,bg0.z,bg0.w,bg1.x,bg1.y,bg1.z,bg1.w};
      const float be[8]={be0.x,be0.y,be0.z,be0.w,be1.x,be1.y,be1.z,be1.w};
      bf16x8 o;
      #pragma unroll
      for (int j=0;j<8;j++){
        const float g = sigm(b2f(p1[j]) + b2f(p2[j]) + bg[j]);
        const float v = fmaxf(b2f(a1[j]) + b2f(a2[j]) + be[j], 0.f) * g;
        o[j] = f2b(v);
      }
      *(bf16x8*)&As[srow][c] = o;
    }
  }

  f32x16 acc[2];
  // ---- emlp2 half 0: ef2 cols 0..127 -> As cols 128..255
  acc[0]=(f32x16)(0.f); acc[1]=(f32x16)(0.f);
  mm32<128,128>(wt_e2, 0, As, Bs, t, lane, w, acc);
  #pragma unroll
  for (int ct=0;ct<2;ct++){
    const int col = (w&1)*64 + ct*32 + lane31;
    const float bb = e2b[col];
    #pragma unroll
    for (int reg=0;reg<16;reg++)
      As[(w>>1)*32 + rowof(reg,kh)][128+col] = f2b(fmaxf(acc[ct][reg] + bb, 0.f));
  }
  // ---- emlp2 half 1: ef2 cols 128..255 -> As cols 0..127 (over ef1)
  acc[0]=(f32x16)(0.f); acc[1]=(f32x16)(0.f);
  mm32<128,128>(wt_e2 + (size_t)128*128, 0, As, Bs, t, lane, w, acc);
  #pragma unroll
  for (int ct=0;ct<2;ct++){
    const int col = (w&1)*64 + ct*32 + lane31;
    const float bb = e2b[128+col];
    #pragma unroll
    for (int reg=0;reg<16;reg++)
      As[(w>>1)*32 + rowof(reg,kh)][col] = f2b(fmaxf(acc[ct][reg] + bb, 0.f));
  }

  // ---- elin1 (256 -> 128) in two K=128 halves (acc carries across calls);
  //      weights k-rotated by 128 at prep time to match As ping-pong layout
  acc[0]=(f32x16)(0.f); acc[1]=(f32x16)(0.f);
  mm32<256,128>(wt_l1,       0,   As, Bs, t, lane, w, acc);
  mm32<256,128>(wt_l1 + 128, 128, As, Bs, t, lane, w, acc);
  {
    const float r_ = rsqrtf(1.f + 1e-5f);
    #pragma unroll
    for (int ct=0;ct<2;ct++){
      const int col = (w&1)*64 + ct*32 + lane31;
      const float sc = ebng[col]*r_, sh = ebnb[col];
      #pragma unroll
      for (int reg=0;reg<16;reg++){
        const float x = fmaf(acc[ct][reg], sc, sh);
        As[(w>>1)*32 + rowof(reg,kh)][col] = f2b((x>0.f)? x : 0.2f*x);
      }
    }
  }

  // ---- elin2 (128 -> 27, padded 32); all waves compute same 32 cols
  f32x16 acc5 = (f32x16)(0.f);
  mm32<128,32>(wt_l2, 0, As, Bs, t, lane, w, &acc5);

  float* Lb = (float*)&As[0][0];   // [64][28] fp32
  if ((w&1)==0 && lane31 < 27){
    #pragma unroll
    for (int reg=0;reg<16;reg++)
      Lb[((w>>1)*32 + rowof(reg,kh))*28 + lane31] = acc5[reg];
  }
  __syncthreads();
  for (int i=t; i<64*27; i+=256){
    int rr = i/27, cc = i - rr*27;
    elog[(size_t)(row0+rr)*27 + cc] = Lb[rr*28 + cc];
  }
}

// ---------------------------- tail kernels --------------------------------
__global__ __launch_bounds__(256) void k_softmax_row(float* __restrict__ x, int M){
  const int wave = threadIdx.x>>6, lane = threadIdx.x&63;
  const int r = blockIdx.x*4 + wave; if (r>=M) return;
  float* p = x + (size_t)r*160;
  float v0 = p[lane], v1 = p[64+lane];
  float v2 = (lane<32)? p[128+lane] : -3.4e38f;
  float m = fmaxf(fmaxf(v0,v1),v2);
  for (int o=32;o;o>>=1) m = fmaxf(m, __shfl_xor(m,o));
  float e0=expf(v0-m), e1=expf(v1-m), e2=(lane<32)?expf(v2-m):0.f;
  float s=e0+e1+e2;
  for (int o=32;o;o>>=1) s += __shfl_xor(s,o);
  float inv = 1.f/s;
  p[lane]=e0*inv; p[64+lane]=e1*inv; if(lane<32)p[128+lane]=e2*inv;
}
__global__ void k_colmax(const float* __restrict__ x, uint32* __restrict__ cmax_u, int E){
  __shared__ float red[8][32];
  const int t=threadIdx.x, col=t&31, seg=t>>5;
  float m = -3.4e38f;
  if (col < 27)
    for (int r = blockIdx.x*8 + seg; r < E; r += gridDim.x*8)
      m = fmaxf(m, x[(size_t)r*27+col]);
  red[seg][col]=m; __syncthreads();
  if (t<32){
    float mm=red[0][t];
    #pragma unroll
    for (int s2=1;s2<8;s2++) mm=fmaxf(mm,red[s2][t]);
    if (t<27){
      uint32 u=__float_as_uint(mm);
      u = (u&0x80000000u)? ~u : (u|0x80000000u);
      atomicMax(&cmax_u[t], u);
    }
  }
}
__global__ void k_colfix(const uint32* __restrict__ cmax_u, float* __restrict__ cmaxf){
  int t=threadIdx.x; if (t>=27) return;
  uint32 u=cmax_u[t];
  cmaxf[t] = (u&0x80000000u)? __uint_as_float(u&0x7FFFFFFFu) : __uint_as_float(~u);
}
__global__ void k_colsum(const float* __restrict__ x, const float* __restrict__ cmaxf,
                         float* __restrict__ csum, int E){
  __shared__ float red[8][32];
  const int t=threadIdx.x, col=t&31, seg=t>>5;
  float s = 0.f;
  if (col < 27){
    const float cm = cmaxf[col];
    for (int r = blockIdx.x*8 + seg; r < E; r += gridDim.x*8)
      s += expf(x[(size_t)r*27+col] - cm);
  }
  red[seg][col]=s; __syncthreads();
  if (t<32){
    float ss=red[0][t];
    #pragma unroll
    for (int s2=1;s2<8;s2++) ss+=red[s2][t];
    if (t<27) atomicAdd(&csum[t], ss);
  }
}
__global__ void k_colnorm(float* __restrict__ x, const float* __restrict__ cmaxf,
                          const float* __restrict__ csum, int E){
  int idx=blockIdx.x*256+threadIdx.x;
  if (idx >= E*27) return;
  int c = idx - (idx/27)*27;
  x[idx] = expf(x[idx]-cmaxf[c]) / csum[c];
}

// ---------------------------------------------------------------------------
extern "C" void kernel_launch(void* const* d_in, const int* in_sizes, int n_in,
                              void* d_out, int out_size, void* d_ws, size_t ws_size,
                              hipStream_t stream)
{
  const float* nf     = (const float*)d_in[0];
  const int*   eidx   = (const int*)  d_in[1];
  const float* gcn1W  = (const float*)d_in[2];
  const float* gcn1b  = (const float*)d_in[3];
  const float* gcn2W  = (const float*)d_in[4];
  const float* gcn2b  = (const float*)d_in[5];
  const float* eattnW = (const float*)d_in[6];
  const float* eattnb = (const float*)d_in[7];
  const float* nattnW = (const float*)d_in[8];
  const float* nattnb = (const float*)d_in[9];
  const float* nredW  = (const float*)d_in[10];
  const float* nredb  = (const float*)d_in[11];
  const float* emlp1W = (const float*)d_in[12];
  const float* emlp1b = (const float*)d_in[13];
  const float* emlp2W = (const float*)d_in[14];
  const float* emlp2b = (const float*)d_in[15];
  const float* nlin1W = (const float*)d_in[16];
  const float* nbng   = (const float*)d_in[17];
  const float* nbnb   = (const float*)d_in[18];
  const float* nlin2W = (const float*)d_in[19];
  const float* elin1W = (const float*)d_in[20];
  const float* ebng   = (const float*)d_in[21];
  const float* ebnb   = (const float*)d_in[22];
  const float* elin2W = (const float*)d_in[23];
  (void)in_sizes; (void)n_in; (void)out_size; (void)ws_size;

  const int N = NN, E = EE;
  float* out  = (float*)d_out;
  float* nlog = out;                       // N*160
  float* elog = out + (size_t)N*160;       // E*27

  // ---- workspace plan (~237 MB, PAs/PAd overlay TUL+h1) ----
  float* ws   = (float*)d_ws;
  float* h2   = ws;                        // N*128
  float* lin2 = ws + (size_t)N*128;        // N*128 ; Q/S early, niB/nx later
  float* Q    = lin2;                      // N*64
  float* S    = lin2 + (size_t)N*64;       // N*64
  float* niB  = lin2;
  float* nx   = lin2;
  float* TUL  = ws + (size_t)N*256;        // N*192  [T|U|lin1]  (dead before k_pa)
  float* h1   = ws + (size_t)N*448;        // N*64              (dead before k_pa)
  short* PAs  = (short*)TUL;               // N*256 bf16
  short* PAd  = PAs + (size_t)N*256;       // N*256 bf16
  float* aei  = ws + (size_t)N*512;        // N*64
  float* dis  = ws + (size_t)N*576;        // N
  float* smalls = ws + (size_t)N*577;      // 96
  float* Wcat = smalls + 128;              // 128*192
  int*   ip   = (int*)(Wcat + 24576);
  int* cntS = ip;                          // N
  int* cntD = ip + N;                      // N
  int* offS = ip + 2*N;                    // N+64
  int* offD = ip + 3*N + 64;               // N+64
  int* curS = ip + 4*N + 128;              // N
  int* curD = ip + 5*N + 128;              // N
  int* csrS = ip + 6*N + 128;              // E
  int* csrD = ip + 6*N + 128 + E;          // E
  int* bsum = ip + 6*N + 128 + 2*E;        // 256
  short* wtb  = (short*)(bsum + 256);
  short* wt_p1 = wtb;                      // 128*128
  short* wt_p2 = wtb + 16384;              // 128*128
  short* wt_a1 = wtb + 32768;              // 128*128
  short* wt_a2 = wtb + 49152;              // 128*128
  short* wt_e2 = wtb + 65536;              // 256*128
  short* wt_l1 = wtb + 98304;              // 128*256
  short* wt_l2 = wtb + 131072;             // 32*128

  const int NB1024 = (N + 1023)/1024;      // 98

  // 0. weight prep
  k_twtg<<<64, 256,0,stream>>>(nredW,  nullptr, wt_p1, 128,128,128, 0,   0);
  k_twtg<<<64, 256,0,stream>>>(nredW,  nullptr, wt_p2, 128,128,128, 128, 0);
  k_twtg<<<64, 256,0,stream>>>(emlp1W, emlp1W+(size_t)128*128, wt_a1, 128,128,128, 0, 0);
  k_twtg<<<64, 256,0,stream>>>(emlp1W, nullptr, wt_a2, 128,128,128, 128, 0);
  k_twtg<<<128,256,0,stream>>>(emlp2W, nullptr, wt_e2, 128,256,256, 0,   0);
  k_twtg<<<128,256,0,stream>>>(elin1W, nullptr, wt_l1, 256,128,128, 0, 128);
  k_twtg<<<16, 256,0,stream>>>(elin2W, nullptr, wt_l2, 128,27, 32,  0,   0);
  k_wprep<<<96,256,0,stream>>>(eattnW, gcn1W, Wcat);

  // 1. CSR build (both directions)
  (void)hipMemsetAsync(cntS, 0, 2*(size_t)N*sizeof(int), stream);
  k_hist<<<(E+255)/256,256,0,stream>>>(eidx, cntS, cntD, E);
  k_scan_sum<<<NB1024,256,0,stream>>>(cntS, bsum, N);
  k_scan_top<<<1,256,0,stream>>>(bsum, NB1024);
  k_scan_out<<<NB1024,256,0,stream>>>(cntS, bsum, offS, N);
  k_scan_sum<<<NB1024,256,0,stream>>>(cntD, bsum, N);
  k_scan_top<<<1,256,0,stream>>>(bsum, NB1024);
  k_scan_out<<<NB1024,256,0,stream>>>(cntD, bsum, offD, N);
  k_setend<<<1,64,0,stream>>>(offS, offD, N, E);
  k_copyoff<<<(N+255)/256,256,0,stream>>>(offS, curS, N);
  k_copyoff<<<(N+255)/256,256,0,stream>>>(offD, curD, N);
  k_fill<<<(E+255)/256,256,0,stream>>>(eidx, curS, curD, csrS, csrD, E);
  k_dis<<<(N+255)/256,256,0,stream>>>(cntD, dis, N);

  // 2. TUL = nf @ [Wbot|Wd|gcn1W]
  gemm_k<128,192,EM_STORE><<<(N+63)/64,256,0,stream>>>(nf, Wcat, nullptr, nullptr, TUL, N);

  // 3. eattn segment means via gathers
  k_gather<64><<<(N+15)/16,256,0,stream>>>(TUL, 192, 0,  offS, csrS, Q, N);
  k_gather<64><<<(N+15)/16,256,0,stream>>>(TUL, 192, 64, offD, csrD, S, N);
  k_aei3<<<(N*16+255)/256,256,0,stream>>>(TUL, Q, S, cntS, cntD, eattnb, aei, N);

  // 4. GCN conv 1
  k_gcnagg<64,true><<<(N+15)/16,256,0,stream>>>(TUL, 192, 128, offD, csrD, dis, aei, gcn1b, h1, N);

  // 5. GCN conv 2
  gemm_k<64,128,EM_STORE><<<(N+63)/64,256,0,stream>>>(h1, gcn2W, nullptr, nullptr, lin2, N);
  k_gcnagg<128,false><<<(N+7)/8,256,0,stream>>>(lin2, 128, 0, offD, csrD, dis, nullptr, gcn2b, h2, N);

  // 6. node attention
  gemm_k<128,128,EM_BRELU><<<(N+63)/64,256,0,stream>>>(h2, nattnW, nattnb, nullptr, niB, N);

  // 7. per-node gate/emlp1 halves (overwrites TUL/h1 region)
  k_pa<<<(N+63)/64,256,0,stream>>>(niB, nf, wt_p1, wt_p2, wt_a1, wt_a2, PAs, PAd, N);

  // 8. fused edge chain (bf16 MFMA 32x32x16, phase-resident weight slab)
  k_edge<<<E/64,256,0,stream>>>(
      PAs, PAd, eidx,
      nredb, emlp1b, wt_e2, emlp2b,
      wt_l1, ebng, ebnb, wt_l2, elog);

  // 9. node head
  gemm_k<128,64,EM_BNLK><<<(N+63)/64,256,0,stream>>>(h2, nlin1W, nbnb, nbng, nx, N);
  gemm_k<64,160,EM_STORE><<<(N+63)/64,256,0,stream>>>(nx, nlin2W, nullptr, nullptr, nlog, N);
  k_softmax_row<<<(N+3)/4,256,0,stream>>>(nlog, N);

  // 10. column softmax over E (in place in d_out)
  (void)hipMemsetAsync(smalls, 0, 96*sizeof(float), stream);
  k_colmax<<<1024,256,0,stream>>>(elog, (uint32*)smalls, E);
  k_colfix<<<1,32,0,stream>>>((const uint32*)smalls, smalls+64);
  k_colsum<<<1024,256,0,stream>>>(elog, smalls+64, smalls+32, E);
  k_colnorm<<<(E*27+255)/256,256,0,stream>>>(elog, smalls+64, smalls+32, E);
}

// Round 16
// 958.967 us; speedup vs baseline: 1.2095x; 1.0656x over previous
//
#include <hip/hip_runtime.h>

#define NN 100000
#define EE 320000

typedef unsigned int uint32;
typedef __attribute__((ext_vector_type(8))) short bf16x8;
typedef __attribute__((ext_vector_type(4))) float f32x4;
typedef __attribute__((ext_vector_type(16))) float f32x16;

__device__ __forceinline__ float4 ld4(const float* p){ return *(const float4*)p; }
__device__ __forceinline__ void st4(float* p, const float4 v){ *(float4*)p = v; }
__device__ __forceinline__ float sigm(float x){ return 1.f/(1.f + expf(-x)); }
__device__ __forceinline__ short f2b(float f){
  union { float f; uint32 u; } v; v.f = f;
  uint32 r = (v.u + 0x7FFFu + ((v.u>>16)&1u)) >> 16;   // RNE
  return (short)r;
}
__device__ __forceinline__ float b2f(short s){
  union { uint32 u; float f; } v; v.u = ((uint32)(unsigned short)s) << 16; return v.f;
}

constexpr int EM_STORE=0, EM_BRELU=1, EM_BNLK=2;

// ---------------------------------------------------------------------------
// Generic fp32 tiled GEMM (node path): 64 rows/block, BK=16, 256 threads.
// ---------------------------------------------------------------------------
template<int K,int NOUT,int EM>
__global__ __launch_bounds__(256) void gemm_k(
    const float* __restrict__ A,
    const float* __restrict__ W, const float* __restrict__ bias,
    const float* __restrict__ bng,
    float* __restrict__ C, int M)
{
  constexpr int CN = NOUT/16;
  __shared__ float As[16][68];
  __shared__ float Ws[16][NOUT];
  const int t  = threadIdx.x;
  const int tx = t & 15, ty = t >> 4;
  const int row0 = blockIdx.x * 64;

  float acc[4][CN];
  #pragma unroll
  for (int i=0;i<4;i++)
    #pragma unroll
    for (int j=0;j<CN;j++) acc[i][j]=0.f;

  const int r_st  = t >> 2;
  const int kq_st = (t & 3) * 4;

  for (int k0=0;k0<K;k0+=16) {
    {
      float4 v = make_float4(0.f,0.f,0.f,0.f);
      const int gr = row0 + r_st;
      if (gr < M) v = ld4(A + (size_t)gr*K + k0 + kq_st);
      As[kq_st+0][r_st]=v.x; As[kq_st+1][r_st]=v.y;
      As[kq_st+2][r_st]=v.z; As[kq_st+3][r_st]=v.w;
    }
    {
      constexpr int C4 = NOUT/4;
      for (int i=t;i<16*C4;i+=256){ int kk=i/C4, c4=(i%C4)*4;
        st4(&Ws[kk][c4], ld4(W + (size_t)(k0+kk)*NOUT + c4)); }
    }
    __syncthreads();
    #pragma unroll
    for (int kk=0;kk<16;kk++){
      float a0,a1,a2,a3;
      { const float4 av = *(const float4*)&As[kk][ty*4]; a0=av.x;a1=av.y;a2=av.z;a3=av.w; }
      float b[CN];
      if constexpr ((CN & 3) == 0) {
        #pragma unroll
        for (int j4=0;j4<CN;j4+=4){
          const float4 bv = *(const float4*)&Ws[kk][tx*CN+j4];
          b[j4]=bv.x;b[j4+1]=bv.y;b[j4+2]=bv.z;b[j4+3]=bv.w; }
      } else {
        #pragma unroll
        for (int j=0;j<CN;j++) b[j]=Ws[kk][tx*CN+j];
      }
      #pragma unroll
      for (int j=0;j<CN;j++){
        acc[0][j]=fmaf(a0,b[j],acc[0][j]);
        acc[1][j]=fmaf(a1,b[j],acc[1][j]);
        acc[2][j]=fmaf(a2,b[j],acc[2][j]);
        acc[3][j]=fmaf(a3,b[j],acc[3][j]);
      }
    }
    __syncthreads();
  }

  float sc[CN], sh[CN];
  if constexpr (EM==EM_BNLK) {
    const float r_ = rsqrtf(1.f + 1e-5f);
    #pragma unroll
    for (int j=0;j<CN;j++){ int c=tx*CN+j; sc[j]=bng[c]*r_; sh[j]=bias[c]; }
  }
  #pragma unroll
  for (int i=0;i<4;i++){
    const int r  = row0 + ty*4+i;
    if (r >= M) continue;
    #pragma unroll
    for (int j=0;j<CN;j++){
      const int c = tx*CN+j;
      float v = acc[i][j];
      if constexpr (EM==EM_BRELU) v = fmaxf(v + bias[c], 0.f);
      else if constexpr (EM==EM_BNLK){ float x = fmaf(v, sc[j], sh[j]); v = (x>0.f)? x : 0.2f*x; }
      C[(size_t)r*NOUT + c] = v;
    }
  }
}

// ---------------------------------------------------------------------------
// CSR build: histogram -> scan -> fill
// ---------------------------------------------------------------------------
__global__ void k_hist(const int* __restrict__ eidx, int* cntS, int* cntD, int E){
  int e = blockIdx.x*256+threadIdx.x; if (e>=E) return;
  atomicAdd(&cntS[eidx[2*e]], 1);
  atomicAdd(&cntD[eidx[2*e+1]], 1);
}
__global__ void k_scan_sum(const int* __restrict__ cnt, int* bsum, int n){
  __shared__ int red[256];
  const int b=blockIdx.x, t=threadIdx.x;
  int s=0;
  for (int i=b*1024+t; i<n && i<(b+1)*1024; i+=256) s += cnt[i];
  red[t]=s; __syncthreads();
  for (int o=128;o;o>>=1){ if(t<o) red[t]+=red[t+o]; __syncthreads(); }
  if (t==0) bsum[b]=red[0];
}
__global__ void k_scan_top(int* bsum, int nb){
  __shared__ int sh[256];
  const int t=threadIdx.x;
  int v=(t<nb)?bsum[t]:0;
  sh[t]=v; __syncthreads();
  for (int o=1;o<256;o<<=1){
    int u=0; if(t>=o) u=sh[t-o];
    __syncthreads();
    sh[t]+=u;
    __syncthreads();
  }
  if (t<nb) bsum[t]=sh[t]-v;
}
// writes exclusive-scan to off AND a working copy to cur (merged k_copyoff)
__global__ void k_scan_out(const int* __restrict__ cnt, const int* __restrict__ bofs,
                           int* __restrict__ off, int* __restrict__ cur, int n){
  __shared__ int sh[256];
  const int b=blockIdx.x, t=threadIdx.x;
  const int base=b*1024+t*4;
  int c0=0,c1=0,c2=0,c3=0;
  if(base+0<n)c0=cnt[base+0];
  if(base+1<n)c1=cnt[base+1];
  if(base+2<n)c2=cnt[base+2];
  if(base+3<n)c3=cnt[base+3];
  int s=c0+c1+c2+c3;
  sh[t]=s; __syncthreads();
  int v=s;
  for (int o=1;o<256;o<<=1){
    int u=0; if(t>=o) u=sh[t-o];
    __syncthreads();
    sh[t]+=u;
    __syncthreads();
  }
  const int tofs = sh[t]-v + bofs[b];
  if(base+0<n){ off[base+0]=tofs;          cur[base+0]=tofs; }
  if(base+1<n){ off[base+1]=tofs+c0;       cur[base+1]=tofs+c0; }
  if(base+2<n){ off[base+2]=tofs+c0+c1;    cur[base+2]=tofs+c0+c1; }
  if(base+3<n){ off[base+3]=tofs+c0+c1+c2; cur[base+3]=tofs+c0+c1+c2; }
}
__global__ void k_setend(int* offS, int* offD, int n, int E){
  if (threadIdx.x==0 && blockIdx.x==0){ offS[n]=E; offD[n]=E; }
}
__global__ void k_fill(const int* __restrict__ eidx, int* curS, int* curD,
                       int* __restrict__ csrS, int* __restrict__ csrD, int E){
  int e=blockIdx.x*256+threadIdx.x; if (e>=E) return;
  const int s=eidx[2*e], d=eidx[2*e+1];
  csrS[atomicAdd(&curS[s],1)] = d;
  csrD[atomicAdd(&curD[d],1)] = s;
}
__global__ void k_dis(const int* __restrict__ cntD, float* __restrict__ dis, int n){
  int i=blockIdx.x*256+threadIdx.x; if(i>=n)return;
  dis[i]=rsqrtf((float)cntD[i]+1.f);
}

// ---------------------------------------------------------------------------
// Wcat = [Wbot | Wd | gcn1W]  (128 x 192 fp32)
// ---------------------------------------------------------------------------
__global__ void k_wprep(const float* __restrict__ eattnW, const float* __restrict__ gcn1W,
                        float* __restrict__ Wcat){
  int idx=blockIdx.x*256+threadIdx.x; if (idx>=128*192) return;
  int k=idx/192, c=idx-k*192;
  float v;
  if (c<64)       v = eattnW[(size_t)(128+k)*64 + c];
  else if (c<128) v = eattnW[(size_t)k*64 + (c-64)] - eattnW[(size_t)(128+k)*64 + (c-64)];
  else            v = gcn1W[(size_t)k*64 + (c-128)];
  Wcat[idx]=v;
}

// ---------------------------------------------------------------------------
// k_fuse1: per node (16 thr/node, 4 cols each):
//   Q = sum_{j in csrS} T[csrS[j]]          (TUL cols 0..63)
//   S = sum_{j in csrD} U[csrD[j]]          (TUL cols 64..127)
//   AG= sum_{j in csrD} dis[s]*L[csrD[j]]   (TUL cols 128..191)
//   aei = sigm(((cS*(U+b)+Q)/max(cS,1)) * ((cD*(T+b)+S)/max(cD,1)))
//   h1  = relu(AG*dn + L*dn^2 + gcn1b) * aei
// Replaces k_gather x2 + k_aei3 + k_gcnagg<64,true> and the Q/S/aei buffers.
// ---------------------------------------------------------------------------
__global__ __launch_bounds__(256) void k_fuse1(
    const float* __restrict__ TUL,
    const int* __restrict__ offS, const int* __restrict__ csrS,
    const int* __restrict__ offD, const int* __restrict__ csrD,
    const int* __restrict__ cntS, const int* __restrict__ cntD,
    const float* __restrict__ dis,
    const float* __restrict__ eattnb, const float* __restrict__ gcn1b,
    float* __restrict__ h1, int n)
{
  const int t = threadIdx.x;
  const int node = blockIdx.x*16 + (t>>4); if (node>=n) return;
  const int cq = (t&15)*4;

  float4 Q = make_float4(0.f,0.f,0.f,0.f);
  {
    const int j1 = offS[node+1];
    for (int j=offS[node]; j<j1; ++j){
      const float4 v = ld4(TUL + (size_t)csrS[j]*192 + cq);
      Q.x+=v.x; Q.y+=v.y; Q.z+=v.z; Q.w+=v.w;
    }
  }
  float4 S = make_float4(0.f,0.f,0.f,0.f);
  float4 AG = make_float4(0.f,0.f,0.f,0.f);
  {
    const int j1 = offD[node+1];
    for (int j=offD[node]; j<j1; ++j){
      const int s = csrD[j];
      const float wgt = dis[s];
      const float* bp = TUL + (size_t)s*192;
      const float4 u = ld4(bp + 64 + cq);
      const float4 L = ld4(bp + 128 + cq);
      S.x+=u.x; S.y+=u.y; S.z+=u.z; S.w+=u.w;
      AG.x=fmaf(L.x,wgt,AG.x); AG.y=fmaf(L.y,wgt,AG.y);
      AG.z=fmaf(L.z,wgt,AG.z); AG.w=fmaf(L.w,wgt,AG.w);
    }
  }
  const float cS=(float)cntS[node], cD=(float)cntD[node];
  const float iS=1.f/fmaxf(cS,1.f), iD=1.f/fmaxf(cD,1.f);
  const float* own = TUL + (size_t)node*192;
  const float4 T4=ld4(own+cq), U4=ld4(own+64+cq), L4=ld4(own+128+cq);
  const float4 b4=ld4(eattnb+cq), g4=ld4(gcn1b+cq);
  float4 aei;
  aei.x = sigm(((cS*(U4.x+b4.x)+Q.x)*iS) * ((cD*(T4.x+b4.x)+S.x)*iD));
  aei.y = sigm(((cS*(U4.y+b4.y)+Q.y)*iS) * ((cD*(T4.y+b4.y)+S.y)*iD));
  aei.z = sigm(((cS*(U4.z+b4.z)+Q.z)*iS) * ((cD*(T4.z+b4.z)+S.z)*iD));
  aei.w = sigm(((cS*(U4.w+b4.w)+Q.w)*iS) * ((cD*(T4.w+b4.w)+S.w)*iD));
  const float dn=dis[node], d2=dn*dn;
  float4 h;
  h.x = fmaxf(fmaf(AG.x,dn,fmaf(L4.x,d2,g4.x)),0.f)*aei.x;
  h.y = fmaxf(fmaf(AG.y,dn,fmaf(L4.y,d2,g4.y)),0.f)*aei.y;
  h.z = fmaxf(fmaf(AG.z,dn,fmaf(L4.z,d2,g4.z)),0.f)*aei.z;
  h.w = fmaxf(fmaf(AG.w,dn,fmaf(L4.w,d2,g4.w)),0.f)*aei.w;
  st4(h1 + (size_t)node*64 + cq, h);
}

// GCN aggregate + combine (conv2 only)
template<int NC, bool AEI>
__global__ void k_gcnagg(const float* __restrict__ lin, int stride, int colbase,
                         const int* __restrict__ off, const int* __restrict__ csr,
                         const float* __restrict__ dis, const float* __restrict__ aei,
                         const float* __restrict__ bias, float* __restrict__ h, int n){
  constexpr int TPN = NC/4;
  const int t=threadIdx.x;
  const int node = blockIdx.x*(256/TPN) + t/TPN; if (node>=n) return;
  const int cq = (t%TPN)*4;
  const int j1=off[node+1];
  float4 acc = make_float4(0.f,0.f,0.f,0.f);
  for (int j=off[node]; j<j1; ++j){
    const int s=csr[j];
    const float w=dis[s];
    const float4 v = ld4(lin + (size_t)s*stride + colbase + cq);
    acc.x=fmaf(v.x,w,acc.x); acc.y=fmaf(v.y,w,acc.y);
    acc.z=fmaf(v.z,w,acc.z); acc.w=fmaf(v.w,w,acc.w);
  }
  const float dn=dis[node], d2=dn*dn;
  const float4 own=ld4(lin + (size_t)node*stride + colbase + cq), b4=ld4(bias+cq);
  float4 o;
  o.x=fmaxf(fmaf(acc.x,dn,fmaf(own.x,d2,b4.x)),0.f);
  o.y=fmaxf(fmaf(acc.y,dn,fmaf(own.y,d2,b4.y)),0.f);
  o.z=fmaxf(fmaf(acc.z,dn,fmaf(own.z,d2,b4.z)),0.f);
  o.w=fmaxf(fmaf(acc.w,dn,fmaf(own.w,d2,b4.w)),0.f);
  if (AEI){ const float4 m=ld4(aei+(size_t)node*NC+cq); o.x*=m.x;o.y*=m.y;o.z*=m.z;o.w*=m.w; }
  st4(h + (size_t)node*NC + cq, o);
}

// ---------------------------------------------------------------------------
// Generic weight transpose + cast: Wt[NP][K] bf16,
// Wt[n][k] = (Wa - Wb?)[((k+krot)%K)+rowoff][n]
// ---------------------------------------------------------------------------
__global__ void k_twtg(const float* __restrict__ Wa, const float* __restrict__ Wb,
                       short* __restrict__ Wt, int K, int N, int NP, int rowoff, int krot){
  int idx = blockIdx.x*256 + threadIdx.x;
  if (idx >= NP*K) return;
  int nn = idx / K, k = idx - nn*K;
  int ks = k + krot; if (ks >= K) ks -= K;
  float v = 0.f;
  if (nn < N){
    v = Wa[(size_t)(ks+rowoff)*N + nn];
    if (Wb) v -= Wb[(size_t)(ks+rowoff)*N + nn];
  }
  Wt[idx] = f2b(v);
}

// ---------------------------------------------------------------------------
// 64-row 32x32x16 MFMA phase, PHASE-RESIDENT WEIGHT SLAB (see R15 notes).
// ---------------------------------------------------------------------------
template<int KSTRIDE, int NCOLTOT>
__device__ __forceinline__ void mm32(
    const short* __restrict__ Wt, int kbase,
    short (*As)[258], short (*Bs)[132],
    int t, int lane, int w, f32x16* acc)
{
  constexpr int NT = (NCOLTOT>=64)? NCOLTOT/64 : 1;
  const int lane31 = lane & 31, kh = lane >> 5;
  const int arow = (w>>1)*32 + lane31;
  const int colbase = (NCOLTOT>=64)? (w&1)*(NCOLTOT/2) : 0;
  {
    constexpr int PER = (NCOLTOT*16)/256;
    #pragma unroll
    for (int p=0;p<PER;p++){
      const int idx = t + p*256;
      const int col = idx >> 4, kq = idx & 15;
      *(float4*)&Bs[col][kq*8] = *(const float4*)(Wt + (size_t)col*KSTRIDE + kq*8);
    }
  }
  __syncthreads();
  #pragma unroll
  for (int ks=0; ks<8; ++ks){
    const bf16x8 a = *(const bf16x8*)&As[arow][kbase + ks*16 + kh*8];
    #pragma unroll
    for (int ct=0; ct<NT; ++ct){
      const bf16x8 b = *(const bf16x8*)&Bs[colbase + ct*32 + lane31][ks*16 + kh*8];
      acc[ct] = __builtin_amdgcn_mfma_f32_32x32x16_bf16(a, b, acc[ct], 0, 0, 0);
    }
  }
  __syncthreads();
}

// C-row within 32-row tile for accumulator register `reg` (m74/m101 layout)
__device__ __forceinline__ int rowof(int reg, int kh){
  return (reg & 3) + ((reg >> 2) << 3) + (kh << 2);
}

// ---------------------------------------------------------------------------
// k_pa2: fused nattn + per-node gate/emlp1 precompute (bf16 MFMA):
//   niB = relu(h2@nattnW + nattnb)        [LDS, bf16 — feeds gate only]
//   PAs[n] = [niB@Wtop(nred) | nf@(W1top-W1bot)]
//   PAd[n] = [niB@Wbot(nred) | nf@W1bot]
// Eliminates the separate 128x128 fp32 nattn GEMM and the niB buffer.
// ---------------------------------------------------------------------------
__global__ __launch_bounds__(256, 2) void k_pa2(
  const float* __restrict__ h2, const float* __restrict__ nf,
  const float* __restrict__ nattnb,
  const short* __restrict__ wt_na,
  const short* __restrict__ wt_p1, const short* __restrict__ wt_p2,
  const short* __restrict__ wt_a1, const short* __restrict__ wt_a2,
  short* __restrict__ PAs, short* __restrict__ PAd, int n)
{
  __shared__ short As[64][258];    // 33024 B
  __shared__ short Bs[128][132];   // 33792 B  -> 66816 total
  short* OutS = &Bs[0][0];         // Out[64][136] aliased into Bs
  const int t = threadIdx.x, lane = t & 63, w = t >> 6;
  const int lane31 = lane & 31, kh = lane >> 5;
  const int n0 = blockIdx.x * 64;
  const int srow = t >> 2, q = t & 3;
  const int grow = n0 + srow;

#define STAGE_SRC(SRC)                                                       \
  {                                                                          \
    short* dst = &As[srow][q*32];                                            \
    if (grow < n){                                                           \
      const float* src = (SRC) + (size_t)grow*128 + q*32;                    \
      _Pragma("unroll")                                                      \
      for (int p=0;p<4;p++){                                                 \
        float4 u=ld4(src+p*8), v=ld4(src+p*8+4);                             \
        bf16x8 o;                                                            \
        o[0]=f2b(u.x);o[1]=f2b(u.y);o[2]=f2b(u.z);o[3]=f2b(u.w);             \
        o[4]=f2b(v.x);o[5]=f2b(v.y);o[6]=f2b(v.z);o[7]=f2b(v.w);             \
        *(bf16x8*)(dst+p*8)=o;                                               \
      }                                                                      \
    } else {                                                                 \
      _Pragma("unroll")                                                      \
      for (int p=0;p<4;p++) *(bf16x8*)(dst+p*8) = (bf16x8)0;                 \
    }                                                                        \
  }

#define OUT_AND_STORE(DST, CB)                                               \
  {                                                                          \
    const int colbase = (w&1)*64;                                            \
    _Pragma("unroll")                                                        \
    for (int ct=0;ct<2;ct++){                                                \
      _Pragma("unroll")                                                      \
      for (int reg=0;reg<16;reg++)                                           \
        OutS[((w>>1)*32 + rowof(reg,kh))*136 + colbase + ct*32 + lane31] =   \
            f2b(acc[ct][reg]);                                               \
    }                                                                        \
    __syncthreads();                                                         \
    if (grow < n){                                                           \
      const float* srcp = (const float*)&OutS[srow*136 + q*32];              \
      float* dstp = (float*)((DST) + (size_t)grow*256 + (CB) + q*32);        \
      _Pragma("unroll")                                                      \
      for (int p=0;p<4;p++) st4(dstp + p*4, ld4(srcp + p*4));                \
    }                                                                        \
    __syncthreads();                                                         \
  }

  f32x16 acc[2];
  // ---- niB = relu(h2 @ nattnW + b) -> As cols 128..255 (bf16)
  STAGE_SRC(h2);
  acc[0]=(f32x16)(0.f); acc[1]=(f32x16)(0.f);
  mm32<128,128>(wt_na, 0, As, Bs, t, lane, w, acc);
  #pragma unroll
  for (int ct=0;ct<2;ct++){
    const int col = (w&1)*64 + ct*32 + lane31;
    const float bb = nattnb[col];
    #pragma unroll
    for (int reg=0;reg<16;reg++)
      As[(w>>1)*32 + rowof(reg,kh)][128+col] = f2b(fmaxf(acc[ct][reg] + bb, 0.f));
  }
  // ---- P1, P2 from niB (As cols 128..255)
  acc[0]=(f32x16)(0.f); acc[1]=(f32x16)(0.f);
  mm32<128,128>(wt_p1, 128, As, Bs, t, lane, w, acc);
  OUT_AND_STORE(PAs, 0);
  acc[0]=(f32x16)(0.f); acc[1]=(f32x16)(0.f);
  mm32<128,128>(wt_p2, 128, As, Bs, t, lane, w, acc);
  OUT_AND_STORE(PAd, 0);
  // ---- A1, A2 from nf (restage As cols 0..127)
  STAGE_SRC(nf);
  acc[0]=(f32x16)(0.f); acc[1]=(f32x16)(0.f);
  mm32<128,128>(wt_a1, 0, As, Bs, t, lane, w, acc);
  OUT_AND_STORE(PAs, 128);
  acc[0]=(f32x16)(0.f); acc[1]=(f32x16)(0.f);
  mm32<128,128>(wt_a2, 0, As, Bs, t, lane, w, acc);
  OUT_AND_STORE(PAd, 128);
#undef STAGE_SRC
#undef OUT_AND_STORE
}

// ---------------------------------------------------------------------------
// Fused edge kernel (unchanged from R15): 64 edges/block, resident slab.
// ---------------------------------------------------------------------------
__global__ __launch_bounds__(256, 2) void k_edge(
  const short* __restrict__ PAs, const short* __restrict__ PAd,
  const int* __restrict__ eidx,
  const float* __restrict__ nredb, const float* __restrict__ e1b,
  const short* __restrict__ wt_e2, const float* __restrict__ e2b,
  const short* __restrict__ wt_l1, const float* __restrict__ ebng, const float* __restrict__ ebnb,
  const short* __restrict__ wt_l2,
  float* __restrict__ elog)
{
  __shared__ short As[64][258];
  __shared__ short Bs[128][132];
  const int t = threadIdx.x, lane = t & 63, w = t >> 6;
  const int lane31 = lane & 31, kh = lane >> 5;
  const int row0 = blockIdx.x * 64;

  {
    const int srow = t >> 2, q = t & 3;
    const int e = row0 + srow;
    const int s = eidx[2*e], d = eidx[2*e+1];
    const short* ps = PAs + (size_t)s*256;
    const short* pd = PAd + (size_t)d*256;
    #pragma unroll
    for (int c0=0;c0<32;c0+=8){
      const int c = q*32 + c0;
      const bf16x8 p1 = *(const bf16x8*)(ps + c);
      const bf16x8 p2 = *(const bf16x8*)(pd + c);
      const bf16x8 a1 = *(const bf16x8*)(ps + 128 + c);
      const bf16x8 a2 = *(const bf16x8*)(pd + 128 + c);
      const float4 bg0=ld4(nredb+c), bg1=ld4(nredb+c+4);
      const float4 be0=ld4(e1b+c),   be1=ld4(e1b+c+4);
      const float bg[8]={bg0.x,bg0.y,bg0.z,bg0.w,bg1.x,bg1.y,bg1.z,bg1.w};
      const float be[8]={be0.x,be0.y,be0.z,be0.w,be1.x,be1.y,be1.z,be1.w};
      bf16x8 o;
      #pragma unroll
      for (int j=0;j<8;j++){
        const float g = sigm(b2f(p1[j]) + b2f(p2[j]) + bg[j]);
        const float v = fmaxf(b2f(a1[j]) + b2f(a2[j]) + be[j], 0.f) * g;
        o[j] = f2b(v);
      }
      *(bf16x8*)&As[srow][c] = o;
    }
  }

  f32x16 acc[2];
  acc[0]=(f32x16)(0.f); acc[1]=(f32x16)(0.f);
  mm32<128,128>(wt_e2, 0, As, Bs, t, lane, w, acc);
  #pragma unroll
  for (int ct=0;ct<2;ct++){
    const int col = (w&1)*64 + ct*32 + lane31;
    const float bb = e2b[col];
    #pragma unroll
    for (int reg=0;reg<16;reg++)
      As[(w>>1)*32 + rowof(reg,kh)][128+col] = f2b(fmaxf(acc[ct][reg] + bb, 0.f));
  }
  acc[0]=(f32x16)(0.f); acc[1]=(f32x16)(0.f);
  mm32<128,128>(wt_e2 + (size_t)128*128, 0, As, Bs, t, lane, w, acc);
  #pragma unroll
  for (int ct=0;ct<2;ct++){
    const int col = (w&1)*64 + ct*32 + lane31;
    const float bb = e2b[128+col];
    #pragma unroll
    for (int reg=0;reg<16;reg++)
      As[(w>>1)*32 + rowof(reg,kh)][col] = f2b(fmaxf(acc[ct][reg] + bb, 0.f));
  }

  acc[0]=(f32x16)(0.f); acc[1]=(f32x16)(0.f);
  mm32<256,128>(wt_l1,       0,   As, Bs, t, lane, w, acc);
  mm32<256,128>(wt_l1 + 128, 128, As, Bs, t, lane, w, acc);
  {
    const float r_ = rsqrtf(1.f + 1e-5f);
    #pragma unroll
    for (int ct=0;ct<2;ct++){
      const int col = (w&1)*64 + ct*32 + lane31;
      const float sc = ebng[col]*r_, sh = ebnb[col];
      #pragma unroll
      for (int reg=0;reg<16;reg++){
        const float x = fmaf(acc[ct][reg], sc, sh);
        As[(w>>1)*32 + rowof(reg,kh)][col] = f2b((x>0.f)? x : 0.2f*x);
      }
    }
  }

  f32x16 acc5 = (f32x16)(0.f);
  mm32<128,32>(wt_l2, 0, As, Bs, t, lane, w, &acc5);

  float* Lb = (float*)&As[0][0];
  if ((w&1)==0 && lane31 < 27){
    #pragma unroll
    for (int reg=0;reg<16;reg++)
      Lb[((w>>1)*32 + rowof(reg,kh))*28 + lane31] = acc5[reg];
  }
  __syncthreads();
  for (int i=t; i<64*27; i+=256){
    int rr = i/27, cc = i - rr*27;
    elog[(size_t)(row0+rr)*27 + cc] = Lb[rr*28 + cc];
  }
}

// ---------------------------- tail kernels --------------------------------
__global__ __launch_bounds__(256) void k_softmax_row(float* __restrict__ x, int M){
  const int wave = threadIdx.x>>6, lane = threadIdx.x&63;
  const int r = blockIdx.x*4 + wave; if (r>=M) return;
  float* p = x + (size_t)r*160;
  float v0 = p[lane], v1 = p[64+lane];
  float v2 = (lane<32)? p[128+lane] : -3.4e38f;
  float m = fmaxf(fmaxf(v0,v1),v2);
  for (int o=32;o;o>>=1) m = fmaxf(m, __shfl_xor(m,o));
  float e0=expf(v0-m), e1=expf(v1-m), e2=(lane<32)?expf(v2-m):0.f;
  float s=e0+e1+e2;
  for (int o=32;o;o>>=1) s += __shfl_xor(s,o);
  float inv = 1.f/s;
  p[lane]=e0*inv; p[64+lane]=e1*inv; if(lane<32)p[128+lane]=e2*inv;
}
__global__ void k_colmax(const float* __restrict__ x, uint32* __restrict__ cmax_u, int E){
  __shared__ float red[8][32];
  const int t=threadIdx.x, col=t&31, seg=t>>5;
  float m = -3.4e38f;
  if (col < 27)
    for (int r = blockIdx.x*8 + seg; r < E; r += gridDim.x*8)
      m = fmaxf(m, x[(size_t)r*27+col]);
  red[seg][col]=m; __syncthreads();
  if (t<32){
    float mm=red[0][t];
    #pragma unroll
    for (int s2=1;s2<8;s2++) mm=fmaxf(mm,red[s2][t]);
    if (t<27){
      uint32 u=__float_as_uint(mm);
      u = (u&0x80000000u)? ~u : (u|0x80000000u);
      atomicMax(&cmax_u[t], u);
    }
  }
}
__global__ void k_colfix(const uint32* __restrict__ cmax_u, float* __restrict__ cmaxf){
  int t=threadIdx.x; if (t>=27) return;
  uint32 u=cmax_u[t];
  cmaxf[t] = (u&0x80000000u)? __uint_as_float(u&0x7FFFFFFFu) : __uint_as_float(~u);
}
__global__ void k_colsum(const float* __restrict__ x, const float* __restrict__ cmaxf,
                         float* __restrict__ csum, int E){
  __shared__ float red[8][32];
  const int t=threadIdx.x, col=t&31, seg=t>>5;
  float s = 0.f;
  if (col < 27){
    const float cm = cmaxf[col];
    for (int r = blockIdx.x*8 + seg; r < E; r += gridDim.x*8)
      s += expf(x[(size_t)r*27+col] - cm);
  }
  red[seg][col]=s; __syncthreads();
  if (t<32){
    float ss=red[0][t];
    #pragma unroll
    for (int s2=1;s2<8;s2++) ss+=red[s2][t];
    if (t<27) atomicAdd(&csum[t], ss);
  }
}
__global__ void k_colnorm(float* __restrict__ x, const float* __restrict__ cmaxf,
                          const float* __restrict__ csum, int E){
  int idx=blockIdx.x*256+threadIdx.x;
  if (idx >= E*27) return;
  int c = idx - (idx/27)*27;
  x[idx] = expf(x[idx]-cmaxf[c]) / csum[c];
}

// ---------------------------------------------------------------------------
extern "C" void kernel_launch(void* const* d_in, const int* in_sizes, int n_in,
                              void* d_out, int out_size, void* d_ws, size_t ws_size,
                              hipStream_t stream)
{
  const float* nf     = (const float*)d_in[0];
  const int*   eidx   = (const int*)  d_in[1];
  const float* gcn1W  = (const float*)d_in[2];
  const float* gcn1b  = (const float*)d_in[3];
  const float* gcn2W  = (const float*)d_in[4];
  const float* gcn2b  = (const float*)d_in[5];
  const float* eattnW = (const float*)d_in[6];
  const float* eattnb = (const float*)d_in[7];
  const float* nattnW = (const float*)d_in[8];
  const float* nattnb = (const float*)d_in[9];
  const float* nredW  = (const float*)d_in[10];
  const float* nredb  = (const float*)d_in[11];
  const float* emlp1W = (const float*)d_in[12];
  const float* emlp1b = (const float*)d_in[13];
  const float* emlp2W = (const float*)d_in[14];
  const float* emlp2b = (const float*)d_in[15];
  const float* nlin1W = (const float*)d_in[16];
  const float* nbng   = (const float*)d_in[17];
  const float* nbnb   = (const float*)d_in[18];
  const float* nlin2W = (const float*)d_in[19];
  const float* elin1W = (const float*)d_in[20];
  const float* ebng   = (const float*)d_in[21];
  const float* ebnb   = (const float*)d_in[22];
  const float* elin2W = (const float*)d_in[23];
  (void)in_sizes; (void)n_in; (void)out_size; (void)ws_size;

  const int N = NN, E = EE;
  float* out  = (float*)d_out;
  float* nlog = out;                       // N*160
  float* elog = out + (size_t)N*160;       // E*27

  // ---- workspace plan (~237 MB, PAs/PAd overlay TUL+h1) ----
  float* ws   = (float*)d_ws;
  float* h2   = ws;                        // N*128
  float* lin2 = ws + (size_t)N*128;        // N*128 ; nx later
  float* nx   = lin2;
  float* TUL  = ws + (size_t)N*256;        // N*192  [T|U|lin1] (dead before k_pa2)
  float* h1   = ws + (size_t)N*448;        // N*64             (dead before k_pa2)
  short* PAs  = (short*)TUL;               // N*256 bf16
  short* PAd  = PAs + (size_t)N*256;       // N*256 bf16
  float* dis  = ws + (size_t)N*576;        // N
  float* smalls = ws + (size_t)N*577;      // 96
  float* Wcat = smalls + 128;              // 128*192
  int*   ip   = (int*)(Wcat + 24576);
  int* cntS = ip;                          // N
  int* cntD = ip + N;                      // N
  int* offS = ip + 2*N;                    // N+64
  int* offD = ip + 3*N + 64;               // N+64
  int* curS = ip + 4*N + 128;              // N
  int* curD = ip + 5*N + 128;              // N
  int* csrS = ip + 6*N + 128;              // E
  int* csrD = ip + 6*N + 128 + E;          // E
  int* bsum = ip + 6*N + 128 + 2*E;        // 256
  short* wtb  = (short*)(bsum + 256);
  short* wt_p1 = wtb;                      // 128*128
  short* wt_p2 = wtb + 16384;              // 128*128
  short* wt_a1 = wtb + 32768;              // 128*128
  short* wt_a2 = wtb + 49152;              // 128*128
  short* wt_e2 = wtb + 65536;              // 256*128
  short* wt_l1 = wtb + 98304;              // 128*256
  short* wt_l2 = wtb + 131072;             // 32*128
  short* wt_na = wtb + 135168;             // 128*128

  const int NB1024 = (N + 1023)/1024;      // 98

  // 0. weight prep
  k_twtg<<<64, 256,0,stream>>>(nredW,  nullptr, wt_p1, 128,128,128, 0,   0);
  k_twtg<<<64, 256,0,stream>>>(nredW,  nullptr, wt_p2, 128,128,128, 128, 0);
  k_twtg<<<64, 256,0,stream>>>(emlp1W, emlp1W+(size_t)128*128, wt_a1, 128,128,128, 0, 0);
  k_twtg<<<64, 256,0,stream>>>(emlp1W, nullptr, wt_a2, 128,128,128, 128, 0);
  k_twtg<<<128,256,0,stream>>>(emlp2W, nullptr, wt_e2, 128,256,256, 0,   0);
  k_twtg<<<128,256,0,stream>>>(elin1W, nullptr, wt_l1, 256,128,128, 0, 128);
  k_twtg<<<16, 256,0,stream>>>(elin2W, nullptr, wt_l2, 128,27, 32,  0,   0);
  k_twtg<<<64, 256,0,stream>>>(nattnW, nullptr, wt_na, 128,128,128, 0,   0);
  k_wprep<<<96,256,0,stream>>>(eattnW, gcn1W, Wcat);

  // 1. CSR build (both directions)
  (void)hipMemsetAsync(cntS, 0, 2*(size_t)N*sizeof(int), stream);
  k_hist<<<(E+255)/256,256,0,stream>>>(eidx, cntS, cntD, E);
  k_scan_sum<<<NB1024,256,0,stream>>>(cntS, bsum, N);
  k_scan_top<<<1,256,0,stream>>>(bsum, NB1024);
  k_scan_out<<<NB1024,256,0,stream>>>(cntS, bsum, offS, curS, N);
  k_scan_sum<<<NB1024,256,0,stream>>>(cntD, bsum, N);
  k_scan_top<<<1,256,0,stream>>>(bsum, NB1024);
  k_scan_out<<<NB1024,256,0,stream>>>(cntD, bsum, offD, curD, N);
  k_setend<<<1,64,0,stream>>>(offS, offD, N, E);
  k_fill<<<(E+255)/256,256,0,stream>>>(eidx, curS, curD, csrS, csrD, E);
  k_dis<<<(N+255)/256,256,0,stream>>>(cntD, dis, N);

  // 2. TUL = nf @ [Wbot|Wd|gcn1W]
  gemm_k<128,192,EM_STORE><<<(N+63)/64,256,0,stream>>>(nf, Wcat, nullptr, nullptr, TUL, N);

  // 3. fused gathers + aei + GCN conv1 -> h1
  k_fuse1<<<(N+15)/16,256,0,stream>>>(TUL, offS, csrS, offD, csrD,
      cntS, cntD, dis, eattnb, gcn1b, h1, N);

  // 4. GCN conv 2
  gemm_k<64,128,EM_STORE><<<(N+63)/64,256,0,stream>>>(h1, gcn2W, nullptr, nullptr, lin2, N);
  k_gcnagg<128,false><<<(N+7)/8,256,0,stream>>>(lin2, 128, 0, offD, csrD, dis, nullptr, gcn2b, h2, N);

  // 5. fused nattn + gate/emlp1 precompute (overwrites TUL/h1 region)
  k_pa2<<<(N+63)/64,256,0,stream>>>(h2, nf, nattnb, wt_na,
      wt_p1, wt_p2, wt_a1, wt_a2, PAs, PAd, N);

  // 6. fused edge chain
  k_edge<<<E/64,256,0,stream>>>(
      PAs, PAd, eidx,
      nredb, emlp1b, wt_e2, emlp2b,
      wt_l1, ebng, ebnb, wt_l2, elog);

  // 7. node head
  gemm_k<128,64,EM_BNLK><<<(N+63)/64,256,0,stream>>>(h2, nlin1W, nbnb, nbng, nx, N);
  gemm_k<64,160,EM_STORE><<<(N+63)/64,256,0,stream>>>(nx, nlin2W, nullptr, nullptr, nlog, N);
  k_softmax_row<<<(N+3)/4,256,0,stream>>>(nlog, N);

  // 8. column softmax over E (in place in d_out)
  (void)hipMemsetAsync(smalls, 0, 96*sizeof(float), stream);
  k_colmax<<<1024,256,0,stream>>>(elog, (uint32*)smalls, E);
  k_colfix<<<1,32,0,stream>>>((const uint32*)smalls, smalls+64);
  k_colsum<<<1024,256,0,stream>>>(elog, smalls+64, smalls+32, E);
  k_colnorm<<<(E*27+255)/256,256,0,stream>>>(elog, smalls+64, smalls+32, E);
}